// Round 7
// baseline (620.343 us; speedup 1.0000x reference)
//
#include <hip/hip_runtime.h>
#include <math.h>

#define N_S 256
#define T_S 20
#define D_S 32
#define NF_S 16
#define Q_S 32
#define HDYN_S 256
#define HDIM_S 1024
#define VSTEPS_S 10
#define DT_S 0.1f
#define LOG2PI_F 1.8378770664093453f

// ---- d_out offsets (floats) ----
#define OUT_XREC 0
#define OUT_QM   5242880
#define OUT_QLV  5259264
#define OUT_ZT   5275648
#define OUT_SCAL 5603328

// ---- workspace offsets (floats) ----
#define WS_A1    0
#define WS_A3    0
#define WS_WT1   0          // 32768  [tap][ci=64][co=32]
#define WS_WT2   32768      // 8192   [tap][ci=32][co=16]
#define WS_WT3   40960      // 256    [tap][ci=16]
#define WS_A2    1048576
#define WS_S0MU  1572864
#define WS_S0LV  1581056
#define WS_V0MU  1589248
#define WS_V0LV  1597440
#define WS_LOGP  1605632
#define WS_LHOOD 1610752
#define WS_KLZ   1611008
#define WS_TC    1611520
#define TC_S1 (WS_TC + 0)
#define TC_V1 (WS_TC + 256)
#define TC_S2 (WS_TC + 2816)
#define TC_V2 (WS_TC + 11008)
#define TC_S3 (WS_TC + 19200)
#define TC_V3 (WS_TC + 51968)

// ---------------- weight transposes ----------------
__device__ inline void enc_tr(const float* __restrict__ src, float* __restrict__ dst,
                              int e, int CI, int CO) {
    int co = e % CO; int r = e / CO; int tap = r & 15; int ci = r >> 4;
    dst[e] = src[(co * CI + ci) * 16 + tap];
}
__device__ inline void dec_tr(const float* __restrict__ src, float* __restrict__ dst,
                              int e, int CI, int CO) {
    int co = e % CO; int r = e / CO; int ci = r % CI; int tap = r / CI;
    dst[e] = src[(co * CI + ci) * 16 + tap];
}

__global__ __launch_bounds__(256) void prep_enc(
    const float* __restrict__ Cs1, const float* __restrict__ Cv1,
    const float* __restrict__ Cs2, const float* __restrict__ Cv2,
    const float* __restrict__ Cs3, const float* __restrict__ Cv3,
    float* __restrict__ ws)
{
    int idx = blockIdx.x * 256 + threadIdx.x;
    if (blockIdx.x == 0) ws[WS_LHOOD + threadIdx.x] = 0.f;
    if (idx < 256)        enc_tr(Cs1, ws + TC_S1, idx,          1, 16);
    else if (idx < 2816)  enc_tr(Cv1, ws + TC_V1, idx - 256,   10, 16);
    else if (idx < 11008) enc_tr(Cs2, ws + TC_S2, idx - 2816,  16, 32);
    else if (idx < 19200) enc_tr(Cv2, ws + TC_V2, idx - 11008, 16, 32);
    else if (idx < 51968) enc_tr(Cs3, ws + TC_S3, idx - 19200, 32, 64);
    else if (idx < 84736) enc_tr(Cv3, ws + TC_V3, idx - 51968, 32, 64);
}

// ---------------- conv1: spatial-split (grid.y = yhalf) ----------------
template<int CIN>
__global__ __launch_bounds__(256) void conv1_lds(
    const float* __restrict__ x, const float* __restrict__ wt,
    const float* __restrict__ bias, float* __restrict__ out)
{
    __shared__ float xin[CIN * 630];
    __shared__ float wl[CIN * 256];
    __shared__ float bl[16];
    int b = blockIdx.x, yh = blockIdx.y, t = threadIdx.x;
    for (int e = t; e < CIN * 576; e += 256) {
        int ci = e / 576;
        int r = (e >> 5) - ci * 18;
        int cx = e & 31;
        int gy = yh * 16 - 1 + r;
        float v = (gy >= 0 && gy < 32) ? x[(size_t)b * 20480 + ci * 1024 + gy * 32 + cx] : 0.f;
        xin[ci * 630 + r * 35 + cx + 1] = v;
    }
    for (int e = t; e < CIN * 18; e += 256) {
        int ci = e / 18, r = e - ci * 18;
        xin[ci * 630 + r * 35 + 0] = 0.f;
        xin[ci * 630 + r * 35 + 33] = 0.f;
    }
    for (int e = t; e < CIN * 256; e += 256) wl[e] = wt[e];
    if (t < 16) bl[t] = bias[t];
    __syncthreads();

    int ocq = t >> 7, p = t & 127;
    int oyl = p >> 4, ox = p & 15;
    float acc[8];
    #pragma unroll
    for (int j = 0; j < 8; j++) acc[j] = bl[ocq * 8 + j];
    for (int ci = 0; ci < CIN; ci++) {
        const float* xc = xin + ci * 630;
        const float* wc = wl + ci * 256 + ocq * 8;
        #pragma unroll
        for (int ky = 0; ky < 4; ky++) {
            const float* xr = xc + (2 * oyl + ky) * 35;
            #pragma unroll
            for (int kx = 0; kx < 4; kx++) {
                float v = xr[2 * ox + kx];
                const float4* w4 = (const float4*)(wc + (ky * 4 + kx) * 16);
                float4 wa = w4[0], wb = w4[1];
                acc[0] = fmaf(v, wa.x, acc[0]);
                acc[1] = fmaf(v, wa.y, acc[1]);
                acc[2] = fmaf(v, wa.z, acc[2]);
                acc[3] = fmaf(v, wa.w, acc[3]);
                acc[4] = fmaf(v, wb.x, acc[4]);
                acc[5] = fmaf(v, wb.y, acc[5]);
                acc[6] = fmaf(v, wb.z, acc[6]);
                acc[7] = fmaf(v, wb.w, acc[7]);
            }
        }
    }
    int oy = yh * 8 + oyl;
    size_t ob = (size_t)b * 4096 + (size_t)(ocq * 8) * 256 + oy * 16 + ox;
    #pragma unroll
    for (int j = 0; j < 8; j++) out[ob + (size_t)j * 256] = fmaxf(acc[j], 0.f);
}

// ---------------- conv2: oc-split (grid.y = half) ----------------
__global__ __launch_bounds__(256) void conv2_lds(
    const float* __restrict__ a1, const float* __restrict__ wt,
    const float* __restrict__ bias, float* __restrict__ out)
{
    __shared__ float xin[16 * 272];
    __shared__ float wl[4096];
    __shared__ float bl[16];
    int b = blockIdx.x, h = blockIdx.y, t = threadIdx.x;
    for (int e = t; e < 4096; e += 256) {
        int ci = e >> 8, r = e & 255, iy = r >> 4, ix = r & 15;
        xin[ci * 272 + iy * 17 + ix] = a1[(size_t)b * 4096 + e];
    }
    for (int e = t; e < 4096; e += 256) {
        int ci = e >> 8, r = e & 255, tap = r >> 4, oc = r & 15;
        wl[e] = wt[ci * 512 + tap * 32 + h * 16 + oc];
    }
    if (t < 16) bl[t] = bias[h * 16 + t];
    __syncthreads();

    int ocq = t >> 6, p = t & 63;
    int pa = p >> 3, pb = p & 7;
    float acc[4];
    #pragma unroll
    for (int j = 0; j < 4; j++) acc[j] = bl[ocq * 4 + j];
    for (int ci = 0; ci < 16; ci++) {
        const float* xc = xin + ci * 272;
        const float* wc = wl + ci * 256 + ocq * 4;
        #pragma unroll
        for (int ky = 0; ky < 4; ky++) {
            int iy = 2 * pa - 1 + ky;
            if ((unsigned)iy >= 16u) continue;
            const float* xr = xc + iy * 17;
            #pragma unroll
            for (int kx = 0; kx < 4; kx++) {
                int ix = 2 * pb - 1 + kx;
                if ((unsigned)ix >= 16u) continue;
                float v = xr[ix];
                float4 wv = *(const float4*)(wc + (ky * 4 + kx) * 16);
                acc[0] = fmaf(v, wv.x, acc[0]);
                acc[1] = fmaf(v, wv.y, acc[1]);
                acc[2] = fmaf(v, wv.z, acc[2]);
                acc[3] = fmaf(v, wv.w, acc[3]);
            }
        }
    }
    size_t ob = (size_t)b * 2048 + (size_t)(h * 16 + ocq * 4) * 64 + pa * 8 + pb;
    #pragma unroll
    for (int j = 0; j < 4; j++) out[ob + (size_t)j * 64] = fmaxf(acc[j], 0.f);
}

// ---------------- conv3b ----------------
__global__ __launch_bounds__(256) void conv3b(
    const float* __restrict__ a2, const float* __restrict__ wt,
    const float* __restrict__ bias, float* __restrict__ out)
{
    __shared__ float xin[32 * 72];
    __shared__ float wl[8192];
    __shared__ float bl[16];
    int b = blockIdx.x, h = blockIdx.y, t = threadIdx.x;
    for (int e = t; e < 2048; e += 256) {
        int ci = e >> 6, r = e & 63, iy = r >> 3, ix = r & 7;
        xin[ci * 72 + iy * 9 + ix] = a2[(size_t)b * 2048 + e];
    }
    for (int e = t; e < 8192; e += 256) {
        int ci = e >> 8, r = e & 255, tap = r >> 4, oc = r & 15;
        wl[e] = wt[ci * 1024 + tap * 64 + h * 16 + oc];
    }
    if (t < 16) bl[t] = bias[h * 16 + t];
    __syncthreads();

    int oc = t >> 4, p = t & 15;
    int pa = p >> 2, pb = p & 3;
    float s0 = bl[oc], s1 = 0.f;
    for (int ci = 0; ci < 32; ci += 2) {
        const float* xc0 = xin + ci * 72;
        const float* wc0 = wl + ci * 256 + oc;
        #pragma unroll
        for (int ky = 0; ky < 4; ky++) {
            int iy = 2 * pa - 1 + ky;
            if ((unsigned)iy >= 8u) continue;
            const float* xr0 = xc0 + iy * 9;
            #pragma unroll
            for (int kx = 0; kx < 4; kx++) {
                int ix = 2 * pb - 1 + kx;
                if ((unsigned)ix >= 8u) continue;
                int wi = (ky * 4 + kx) * 16;
                s0 = fmaf(xr0[ix],      wc0[wi],       s0);
                s1 = fmaf(xr0[72 + ix], wc0[256 + wi], s1);
            }
        }
    }
    out[(size_t)b * 1024 + h * 256 + t] = fmaxf(s0 + s1, 0.f);
}

// ---------------- encoder fc ----------------
__global__ __launch_bounds__(256) void fc_enc2(
    const float* __restrict__ h,
    const float* __restrict__ Wm, const float* __restrict__ bm,
    const float* __restrict__ Wl, const float* __restrict__ bl,
    float* __restrict__ mu, float* __restrict__ lv)
{
    __shared__ float pm[8][32], pl[8][32];
    int b = blockIdx.x, t = threadIdx.x;
    int q = t & 31, c = t >> 5;
    const float* hb = h + (size_t)b * HDIM_S + c * 128;
    const float* wmp = Wm + (c * 128) * Q_S + q;
    const float* wlp = Wl + (c * 128) * Q_S + q;
    float am = 0.f, al = 0.f;
    #pragma unroll 4
    for (int k = 0; k < 128; k++) {
        float hv = hb[k];
        am = fmaf(hv, wmp[k * Q_S], am);
        al = fmaf(hv, wlp[k * Q_S], al);
    }
    pm[c][q] = am; pl[c][q] = al;
    __syncthreads();
    if (t < 32) {
        float s = bm[t];
        #pragma unroll
        for (int c2 = 0; c2 < 8; c2++) s += pm[c2][t];
        mu[b * Q_S + t] = s;
    } else if (t < 64) {
        int qq = t - 32;
        float s = bl[qq];
        #pragma unroll
        for (int c2 = 0; c2 < 8; c2++) s += pl[c2][qq];
        lv[b * Q_S + qq] = s;
    }
}

// ---------------- reparameterize + decoder weight transpose ----------------
__global__ __launch_bounds__(256) void reparam_prep(
    const float* __restrict__ s0mu, const float* __restrict__ s0lv,
    const float* __restrict__ v0mu, const float* __restrict__ v0lv,
    const float* __restrict__ eps_s, const float* __restrict__ eps_v,
    const float* __restrict__ D1, const float* __restrict__ D2,
    const float* __restrict__ D3,
    float* __restrict__ ws,
    float* __restrict__ qm, float* __restrict__ qlv,
    float* __restrict__ ztL, float* __restrict__ logp)
{
    int n = blockIdx.x, t = threadIdx.x;
    int idx = n * 256 + t;
    if (idx < 32768)      dec_tr(D1, ws + WS_WT1, idx,         64, 32);
    else if (idx < 40960) dec_tr(D2, ws + WS_WT2, idx - 32768, 32, 16);
    else if (idx < 41216) dec_tr(D3, ws + WS_WT3, idx - 40960, 16, 1);
    if (t < 64) {
        int q = t & 31;
        float mu, lvv, ep;
        if (t < 32) { mu = v0mu[n*32+q]; lvv = v0lv[n*32+q]; ep = eps_v[n*32+q]; }
        else        { mu = s0mu[n*32+q]; lvv = s0lv[n*32+q]; ep = eps_s[n*32+q]; }
        float zv = fmaf(ep, expf(lvv), mu);
        qm[n*64 + t]  = mu;
        qlv[n*64 + t] = lvv;
        ztL[(size_t)n * T_S * 64 + t] = zv;
        float e2 = ep * ep;
        #pragma unroll
        for (int off = 32; off; off >>= 1) e2 += __shfl_down(e2, off, 64);
        if (t == 0) logp[n * T_S] = -0.5f * e2 - Q_S * LOG2PI_F;
    }
}

// ---------------- RK4 ODE (vectorized LDS broadcast reads) + fused klz -------------
__global__ __launch_bounds__(256) void ode_kernel(
    const float* __restrict__ W1, const float* __restrict__ b1,
    const float* __restrict__ W2, const float* __restrict__ b2,
    float* __restrict__ ztL, float* __restrict__ logp, float* __restrict__ klz)
{
    __shared__ float W2s[HDYN_S * Q_S];
    __shared__ float zeval[64];
    __shared__ float hsh[HDYN_S];
    __shared__ float dvred[HDYN_S];
    __shared__ float red4[4];
    int n = blockIdx.x;
    int t = threadIdx.x;

    for (int i = t; i < HDYN_S * Q_S; i += 256) W2s[i] = W2[i];
    float w1r[64];
    #pragma unroll
    for (int j = 0; j < 64; j++) w1r[j] = W1[j * HDYN_S + t];
    float b1r = b1[t];
    __syncthreads();
    float ck = 0.f;
    #pragma unroll
    for (int i = 0; i < Q_S; i++) ck = fmaf(w1r[i], W2s[t * Q_S + i], ck);

    size_t zoff = (size_t)n * T_S * 64;
    float zj = 0.f, ksumj = 0.f, zevalj = 0.f, lp = 0.f, lsum = 0.f, klzacc = 0.f;
    if (t < 64) { zj = ztL[zoff + t]; zevalj = zj; zeval[t] = zj; }
    if (t == 0) lp = logp[n * T_S];
    {
        float e2z = zj * zj;
        #pragma unroll
        for (int off = 32; off; off >>= 1) e2z += __shfl_down(e2z, off, 64);
        if (t == 0) klzacc = lp + 0.5f * e2z + Q_S * LOG2PI_F;
    }

    const float wc[4] = {1.f, 2.f, 2.f, 1.f};
    const float ac[3] = {0.5f * DT_S, 0.5f * DT_S, DT_S};

    for (int step = 1; step < T_S; step++) {
        for (int e = 0; e < 4; e++) {
            __syncthreads();
            float p0 = 0.f, p1 = 0.f, p2 = 0.f, p3 = 0.f;
            const float4* ze4 = (const float4*)zeval;
            #pragma unroll
            for (int jj = 0; jj < 4; jj++) {
                float4 za = ze4[jj], zb = ze4[jj + 4], zc = ze4[jj + 8], zd = ze4[jj + 12];
                p0 = fmaf(za.x, w1r[jj*4+0], p0);
                p0 = fmaf(za.y, w1r[jj*4+1], p0);
                p0 = fmaf(za.z, w1r[jj*4+2], p0);
                p0 = fmaf(za.w, w1r[jj*4+3], p0);
                p1 = fmaf(zb.x, w1r[16+jj*4+0], p1);
                p1 = fmaf(zb.y, w1r[16+jj*4+1], p1);
                p1 = fmaf(zb.z, w1r[16+jj*4+2], p1);
                p1 = fmaf(zb.w, w1r[16+jj*4+3], p1);
                p2 = fmaf(zc.x, w1r[32+jj*4+0], p2);
                p2 = fmaf(zc.y, w1r[32+jj*4+1], p2);
                p2 = fmaf(zc.z, w1r[32+jj*4+2], p2);
                p2 = fmaf(zc.w, w1r[32+jj*4+3], p2);
                p3 = fmaf(zd.x, w1r[48+jj*4+0], p3);
                p3 = fmaf(zd.y, w1r[48+jj*4+1], p3);
                p3 = fmaf(zd.z, w1r[48+jj*4+2], p3);
                p3 = fmaf(zd.w, w1r[48+jj*4+3], p3);
            }
            float pre = b1r + ((p0 + p1) + (p2 + p3));
            float hk = tanhf(pre);
            hsh[t] = hk;
            float gk = (1.f - hk * hk) * ck;
            #pragma unroll
            for (int off = 32; off; off >>= 1) gk += __shfl_down(gk, off, 64);
            if ((t & 63) == 0) red4[t >> 6] = gk;
            __syncthreads();
            {
                int i = t & 31, p = t >> 5;
                const float4* h4 = (const float4*)(hsh + p * 32);
                const float* wbase = W2s + (p * 32) * Q_S + i;
                float a0 = 0.f, a1 = 0.f;
                #pragma unroll
                for (int k4 = 0; k4 < 4; k4++) {
                    float4 ha = h4[k4], hb = h4[k4 + 4];
                    const float* wk = wbase + k4 * 4 * Q_S;
                    a0 = fmaf(ha.x, wk[0],        a0);
                    a0 = fmaf(ha.y, wk[Q_S],      a0);
                    a0 = fmaf(ha.z, wk[2*Q_S],    a0);
                    a0 = fmaf(ha.w, wk[3*Q_S],    a0);
                    const float* wk2 = wbase + (16 + k4 * 4) * Q_S;
                    a1 = fmaf(hb.x, wk2[0],       a1);
                    a1 = fmaf(hb.y, wk2[Q_S],     a1);
                    a1 = fmaf(hb.z, wk2[2*Q_S],   a1);
                    a1 = fmaf(hb.w, wk2[3*Q_S],   a1);
                }
                dvred[t] = a0 + a1;
            }
            __syncthreads();
            if (t < 64) {
                float tr = red4[0] + red4[1] + red4[2] + red4[3];
                float zv_shfl = __shfl(zevalj, (t >= 32) ? (t - 32) : t, 64);
                float kzv;
                if (t < 32) {
                    float dvi = b2[t];
                    #pragma unroll
                    for (int p = 0; p < 8; p++) dvi += dvred[p * 32 + t];
                    kzv = dvi;
                } else kzv = zv_shfl;
                if (e == 0) ksumj = kzv; else ksumj = fmaf(wc[e], kzv, ksumj);
                if (t == 0) { float kl = -tr; lsum = (e == 0) ? kl : fmaf(wc[e], kl, lsum); }
                if (e < 3) {
                    zevalj = fmaf(ac[e], kzv, zj);
                    zeval[t] = zevalj;
                } else {
                    zj = fmaf(DT_S / 6.f, ksumj, zj);
                    zevalj = zj; zeval[t] = zj;
                    ztL[zoff + step * 64 + t] = zj;
                    float e2z = zj * zj;
                    #pragma unroll
                    for (int off = 32; off; off >>= 1) e2z += __shfl_down(e2z, off, 64);
                    if (t == 0) {
                        lp = fmaf(DT_S / 6.f, lsum, lp);
                        logp[n * T_S + step] = lp;
                        klzacc += lp + 0.5f * e2z + Q_S * LOG2PI_F;
                    }
                }
            }
        }
    }
    if (t == 0) klz[n] = klzacc;
}

// ---------------- fused decoder v7: verified-uniform bank layouts ----------------
// slp: row(iy) 276 fl [69u], pos(ix) 68 fl [17u], ci; zero-line u2[5264..5331]
// h1 : plane 592 fl [148u≡4], row(ly) 148 fl [37u odd], pos(lx) 36 fl [9u odd];
//      zero-line h1s[2368..2403]
// h2 : plane 1316 fl [329u], row(ly) 164 fl [41u], pos(lx) 20 fl [5u odd]
// xst: 32 rows x 36 (aliases h1s)
__global__ __launch_bounds__(256) void decoder7(
    const float* __restrict__ ztL, const float* __restrict__ Wf, const float* __restrict__ bf,
    const float* __restrict__ wt1, const float* __restrict__ d1,
    const float* __restrict__ wt2, const float* __restrict__ d2,
    const float* __restrict__ wt3, const float* __restrict__ d3,
    const float* __restrict__ X, float* __restrict__ Xrec, float* __restrict__ lhood)
{
    __shared__ float zs[32];
    __shared__ float h1s[2404];
    __shared__ float u2[5332];
    __shared__ float sh4[4];
    float* slp = u2;
    float* h2p = u2;
    float* xst = h1s;
    const int bidx = blockIdx.x;
    const int t = threadIdx.x;
    const int wu = __builtin_amdgcn_readfirstlane(t >> 6);
    const int l = t & 63;
    const int py = wu >> 1, px = wu & 1;

    if (t < 32) zs[t] = ztL[(size_t)bidx * 64 + 32 + t];
    if (t < 68) u2[5264 + t] = 0.f;
    if (t < 36) h1s[2368 + t] = 0.f;
    __syncthreads();

    // ---- fc3: s = z_s @ Wf + bf -> slp ----
    {
        float4 acc = ((const float4*)bf)[t];
        const float4* Wf4 = (const float4*)Wf;
        #pragma unroll 4
        for (int q = 0; q < 32; q++) {
            float zq = zs[q];
            float4 wv = Wf4[q * 256 + t];
            acc.x = fmaf(zq, wv.x, acc.x);
            acc.y = fmaf(zq, wv.y, acc.y);
            acc.z = fmaf(zq, wv.z, acc.z);
            acc.w = fmaf(zq, wv.w, acc.w);
        }
        int k0 = t * 4;
        int ci = k0 >> 4;
        int iy = t & 3;               // p0 = 4*(t&3); iy = p0>>2
        float vv[4] = {acc.x, acc.y, acc.z, acc.w};
        #pragma unroll
        for (int j = 0; j < 4; j++)
            slp[iy * 276 + j * 68 + ci] = vv[j];
    }
    __syncthreads();

    // ---- deconv1: [4,4,64] -> parity planes of [8,8,32]; thread = 2pos x 4oc ----
    {
        int ocq = l >> 3;
        int pp = l & 7;
        int a_ = pp >> 1, b2 = pp & 1;
        float acc0[4], acc1[4];
        #pragma unroll
        for (int j = 0; j < 4; j++) { acc0[j] = d1[ocq * 4 + j]; acc1[j] = acc0[j]; }
        #pragma unroll
        for (int sy = 0; sy < 2; sy++) {
            int ky = py + 2 * sy;
            int iy = a_ + py + sy - 1;
            bool rowok = (unsigned)iy < 4u;
            #pragma unroll
            for (int sx = 0; sx < 2; sx++) {
                int kx = px + 2 * sx;
                int ix0 = 2 * b2 + px + sx - 1;
                int ix1 = ix0 + 1;
                int off0 = (rowok && (unsigned)ix0 < 4u) ? (iy * 276 + ix0 * 68) : 5264;
                int off1 = (rowok && (unsigned)ix1 < 4u) ? (iy * 276 + ix1 * 68) : 5264;
                const float4* ip0 = (const float4*)(u2 + off0);
                const float4* ip1 = (const float4*)(u2 + off1);
                const float* wb = wt1 + (ky * 4 + kx) * 2048 + ocq * 4;
                #pragma unroll 4
                for (int cc = 0; cc < 16; cc++) {
                    float4 va = ip0[cc];
                    float4 vb = ip1[cc];
                    float av[4] = {va.x, va.y, va.z, va.w};
                    float bv[4] = {vb.x, vb.y, vb.z, vb.w};
                    #pragma unroll
                    for (int r = 0; r < 4; r++) {
                        float4 wv = *(const float4*)(wb + (cc * 4 + r) * 32);
                        acc0[0] = fmaf(av[r], wv.x, acc0[0]); acc1[0] = fmaf(bv[r], wv.x, acc1[0]);
                        acc0[1] = fmaf(av[r], wv.y, acc0[1]); acc1[1] = fmaf(bv[r], wv.y, acc1[1]);
                        acc0[2] = fmaf(av[r], wv.z, acc0[2]); acc1[2] = fmaf(bv[r], wv.z, acc1[2]);
                        acc0[3] = fmaf(av[r], wv.w, acc0[3]); acc1[3] = fmaf(bv[r], wv.w, acc1[3]);
                    }
                }
            }
        }
        float* hp = h1s + (py * 2 + px) * 592;
        int ox0 = 2 * b2, ox1 = ox0 + 1;
        float4 r0, r1;
        r0.x = fmaxf(acc0[0],0.f); r0.y = fmaxf(acc0[1],0.f); r0.z = fmaxf(acc0[2],0.f); r0.w = fmaxf(acc0[3],0.f);
        r1.x = fmaxf(acc1[0],0.f); r1.y = fmaxf(acc1[1],0.f); r1.z = fmaxf(acc1[2],0.f); r1.w = fmaxf(acc1[3],0.f);
        *(float4*)(hp + a_ * 148 + ox0 * 36 + ocq * 4) = r0;
        *(float4*)(hp + a_ * 148 + ox1 * 36 + ocq * 4) = r1;
    }
    __syncthreads();

    // ---- deconv2: thread = 1 pos x 16 oc; wave-uniform weights ----
    {
        int a = l >> 3, b = l & 7;
        float acc[16];
        #pragma unroll
        for (int j = 0; j < 16; j++) acc[j] = d2[j];
        #pragma unroll
        for (int sy = 0; sy < 2; sy++) {
            int ky = py + 2 * sy;
            int iyf = a + py + sy - 1;
            int pyi = iyf & 1, ly = iyf >> 1;
            bool yok = (unsigned)iyf < 8u;
            #pragma unroll
            for (int sx = 0; sx < 2; sx++) {
                int kx = px + 2 * sx;
                int ixf = b + px + sx - 1;
                int pxi = ixf & 1, lx = ixf >> 1;
                int off = (yok && (unsigned)ixf < 8u)
                          ? ((pyi * 2 + pxi) * 592 + ly * 148 + lx * 36) : 2368;
                const float4* ip4 = (const float4*)(h1s + off);
                const float* wb = wt2 + (ky * 4 + kx) * 512;
                #pragma unroll 2
                for (int cc = 0; cc < 8; cc++) {
                    float4 v = ip4[cc];
                    float vv[4] = {v.x, v.y, v.z, v.w};
                    #pragma unroll
                    for (int r = 0; r < 4; r++) {
                        const float4* wq = (const float4*)(wb + (cc * 4 + r) * 16);
                        float4 w0 = wq[0], w1 = wq[1], w2 = wq[2], w3 = wq[3];
                        float vr = vv[r];
                        acc[0]  = fmaf(vr, w0.x, acc[0]);
                        acc[1]  = fmaf(vr, w0.y, acc[1]);
                        acc[2]  = fmaf(vr, w0.z, acc[2]);
                        acc[3]  = fmaf(vr, w0.w, acc[3]);
                        acc[4]  = fmaf(vr, w1.x, acc[4]);
                        acc[5]  = fmaf(vr, w1.y, acc[5]);
                        acc[6]  = fmaf(vr, w1.z, acc[6]);
                        acc[7]  = fmaf(vr, w1.w, acc[7]);
                        acc[8]  = fmaf(vr, w2.x, acc[8]);
                        acc[9]  = fmaf(vr, w2.y, acc[9]);
                        acc[10] = fmaf(vr, w2.z, acc[10]);
                        acc[11] = fmaf(vr, w2.w, acc[11]);
                        acc[12] = fmaf(vr, w3.x, acc[12]);
                        acc[13] = fmaf(vr, w3.y, acc[13]);
                        acc[14] = fmaf(vr, w3.z, acc[14]);
                        acc[15] = fmaf(vr, w3.w, acc[15]);
                    }
                }
            }
        }
        float* hq = h2p + (py * 2 + px) * 1316 + a * 164 + b * 20;
        #pragma unroll
        for (int j = 0; j < 4; j++) {
            float4 r;
            r.x = fmaxf(acc[j*4+0], 0.f);
            r.y = fmaxf(acc[j*4+1], 0.f);
            r.z = fmaxf(acc[j*4+2], 0.f);
            r.w = fmaxf(acc[j*4+3], 0.f);
            *(float4*)(hq + j * 4) = r;
        }
    }
    __syncthreads();

    // ---- deconv3: 2x2 output tile/thread, 9 shared input pixels ----
    {
        int u = l >> 3, v = l & 7;
        int ib = 2 * u + py - 1;
        int jb = 2 * v + px - 1;
        int offp[3][3];
        #pragma unroll
        for (int r = 0; r < 3; r++) {
            int iy = ib + r;
            int pyi = iy & 1, ly = iy >> 1;
            bool yok = (unsigned)iy < 16u;
            #pragma unroll
            for (int c = 0; c < 3; c++) {
                int ix = jb + c;
                int pxi = ix & 1, lx = ix >> 1;
                offp[r][c] = (yok && (unsigned)ix < 16u)
                             ? ((pyi * 2 + pxi) * 1316 + ly * 164 + lx * 20) : 5264;
            }
        }
        float d30 = d3[0];
        float acc[4] = {d30, d30, d30, d30};
        #pragma unroll
        for (int cc = 0; cc < 4; cc++) {
            float4 pix[3][3];
            #pragma unroll
            for (int r = 0; r < 3; r++)
                #pragma unroll
                for (int c = 0; c < 3; c++)
                    pix[r][c] = ((const float4*)(u2 + offp[r][c]))[cc];
            #pragma unroll
            for (int sy = 0; sy < 2; sy++) {
                int ky = py + 2 * sy;
                #pragma unroll
                for (int sx = 0; sx < 2; sx++) {
                    int kx = px + 2 * sx;
                    float4 wq = ((const float4*)(wt3 + (ky * 4 + kx) * 16))[cc];
                    #pragma unroll
                    for (int dy = 0; dy < 2; dy++) {
                        #pragma unroll
                        for (int dx = 0; dx < 2; dx++) {
                            float4 p4 = pix[dy + sy][dx + sx];
                            float s = acc[dy * 2 + dx];
                            s = fmaf(p4.x, wq.x, s);
                            s = fmaf(p4.y, wq.y, s);
                            s = fmaf(p4.z, wq.z, s);
                            s = fmaf(p4.w, wq.w, s);
                            acc[dy * 2 + dx] = s;
                        }
                    }
                }
            }
        }
        #pragma unroll
        for (int dy = 0; dy < 2; dy++) {
            #pragma unroll
            for (int dx = 0; dx < 2; dx++) {
                int oy = 4 * u + 2 * dy + py;
                int ox = 4 * v + 2 * dx + px;
                xst[oy * 36 + ox] = 1.f / (1.f + expf(-acc[dy * 2 + dx]));
            }
        }
    }
    __syncthreads();

    // ---- coalesced Xrec write + X read + lhood ----
    {
        int row = t >> 3, col = (t & 7) * 4;
        float4 xr4 = *(const float4*)(xst + row * 36 + col);
        *(float4*)(Xrec + (size_t)bidx * 1024 + t * 4) = xr4;
        float4 xi4 = *(const float4*)(X + (size_t)bidx * 1024 + t * 4);
        float ll = 0.f;
        ll += logf(0.001f + xr4.x) * xi4.x + logf(1.001f - xr4.x) * (1.f - xi4.x);
        ll += logf(0.001f + xr4.y) * xi4.y + logf(1.001f - xr4.y) * (1.f - xi4.y);
        ll += logf(0.001f + xr4.z) * xi4.z + logf(1.001f - xr4.z) * (1.f - xi4.z);
        ll += logf(0.001f + xr4.w) * xi4.w + logf(1.001f - xr4.w) * (1.f - xi4.w);
        #pragma unroll
        for (int off = 32; off; off >>= 1) ll += __shfl_down(ll, off, 64);
        if ((t & 63) == 0) sh4[t >> 6] = ll;
    }
    __syncthreads();
    if (t == 0) atomicAdd(&lhood[bidx / T_S], sh4[0] + sh4[1] + sh4[2] + sh4[3]);
}

// ---------------- final scalars (+ kl_w fused) ----------------
__global__ __launch_bounds__(256) void final2(
    const float* __restrict__ lhood, const float* __restrict__ klz,
    const float* __restrict__ W1, const float* __restrict__ W2,
    const int* __restrict__ Ndata, float* __restrict__ outs)
{
    __shared__ float shA[4], shB[4], shC[4];
    int t = threadIdx.x;
    float a = lhood[t];
    float b = klz[t];
    float c = 0.f;
    for (int i = t; i < 64 * HDYN_S; i += 256) c = fmaf(W1[i], W1[i], c);
    for (int i = t; i < HDYN_S * Q_S; i += 256) c = fmaf(W2[i], W2[i], c);
    #pragma unroll
    for (int off = 32; off; off >>= 1) {
        a += __shfl_down(a, off, 64);
        b += __shfl_down(b, off, 64);
        c += __shfl_down(c, off, 64);
    }
    if ((t & 63) == 0) { shA[t >> 6] = a; shB[t >> 6] = b; shC[t >> 6] = c; }
    __syncthreads();
    if (t == 0) {
        float Nd = (float)Ndata[0];
        float lh = Nd * ((shA[0] + shA[1] + shA[2] + shA[3]) / 256.f);
        float kz = Nd * ((shB[0] + shB[1] + shB[2] + shB[3]) / 256.f);
        float bkw = 0.5f * (shC[0] + shC[1] + shC[2] + shC[3]);
        outs[0] = lh - kz - bkw;
        outs[1] = lh;
        outs[2] = kz;
        outs[3] = bkw;
    }
}

extern "C" void kernel_launch(void* const* d_in, const int* in_sizes, int n_in,
                              void* d_out, int out_size, void* d_ws, size_t ws_size,
                              hipStream_t stream) {
    const float* X      = (const float*)d_in[0];
    const float* eps_s0 = (const float*)d_in[1];
    const float* eps_v0 = (const float*)d_in[2];
    const float* Cs1 = (const float*)d_in[3],  *cs1 = (const float*)d_in[4];
    const float* Cs2 = (const float*)d_in[5],  *cs2 = (const float*)d_in[6];
    const float* Cs3 = (const float*)d_in[7],  *cs3 = (const float*)d_in[8];
    const float* Wsm = (const float*)d_in[9],  *bsm = (const float*)d_in[10];
    const float* Wsl = (const float*)d_in[11], *bsl = (const float*)d_in[12];
    const float* Cv1 = (const float*)d_in[13], *cv1 = (const float*)d_in[14];
    const float* Cv2 = (const float*)d_in[15], *cv2 = (const float*)d_in[16];
    const float* Cv3 = (const float*)d_in[17], *cv3 = (const float*)d_in[18];
    const float* Wvm = (const float*)d_in[19], *bvm = (const float*)d_in[20];
    const float* Wvl = (const float*)d_in[21], *bvl = (const float*)d_in[22];
    const float* W1  = (const float*)d_in[23], *b1  = (const float*)d_in[24];
    const float* W2  = (const float*)d_in[25], *b2  = (const float*)d_in[26];
    const float* Wf  = (const float*)d_in[27], *bf  = (const float*)d_in[28];
    const float* D1  = (const float*)d_in[29], *d1  = (const float*)d_in[30];
    const float* D2  = (const float*)d_in[31], *d2  = (const float*)d_in[32];
    const float* D3  = (const float*)d_in[33], *d3  = (const float*)d_in[34];
    const int*   Ndata = (const int*)d_in[35];

    float* out = (float*)d_out;
    float* ws  = (float*)d_ws;

    prep_enc<<<331, 256, 0, stream>>>(Cs1, Cv1, Cs2, Cv2, Cs3, Cv3, ws);

    // ---- encoder s (frame 0) ----
    conv1_lds<1><<<dim3(256, 2), 256, 0, stream>>>(X, ws + TC_S1, cs1, ws + WS_A1);
    conv2_lds<<<dim3(256, 2), 256, 0, stream>>>(ws + WS_A1, ws + TC_S2, cs2, ws + WS_A2);
    conv3b<<<dim3(256, 4), 256, 0, stream>>>(ws + WS_A2, ws + TC_S3, cs3, ws + WS_A3);
    fc_enc2<<<256, 256, 0, stream>>>(ws + WS_A3, Wsm, bsm, Wsl, bsl, ws + WS_S0MU, ws + WS_S0LV);

    // ---- encoder v (10 frames as channels) ----
    conv1_lds<10><<<dim3(256, 2), 256, 0, stream>>>(X, ws + TC_V1, cv1, ws + WS_A1);
    conv2_lds<<<dim3(256, 2), 256, 0, stream>>>(ws + WS_A1, ws + TC_V2, cv2, ws + WS_A2);
    conv3b<<<dim3(256, 4), 256, 0, stream>>>(ws + WS_A2, ws + TC_V3, cv3, ws + WS_A3);
    fc_enc2<<<256, 256, 0, stream>>>(ws + WS_A3, Wvm, bvm, Wvl, bvl, ws + WS_V0MU, ws + WS_V0LV);

    // ---- reparameterize + decoder weight transpose ----
    reparam_prep<<<256, 256, 0, stream>>>(ws + WS_S0MU, ws + WS_S0LV, ws + WS_V0MU, ws + WS_V0LV,
                                          eps_s0, eps_v0, D1, D2, D3, ws,
                                          out + OUT_QM, out + OUT_QLV,
                                          out + OUT_ZT, ws + WS_LOGP);

    // ---- RK4 ODE (+klz) ----
    ode_kernel<<<256, 256, 0, stream>>>(W1, b1, W2, b2, out + OUT_ZT, ws + WS_LOGP,
                                        ws + WS_KLZ);

    // ---- fused decoder ----
    decoder7<<<5120, 256, 0, stream>>>(out + OUT_ZT, Wf, bf,
                                       ws + WS_WT1, d1, ws + WS_WT2, d2, ws + WS_WT3, d3,
                                       X, out + OUT_XREC, ws + WS_LHOOD);

    // ---- final scalars ----
    final2<<<1, 256, 0, stream>>>(ws + WS_LHOOD, ws + WS_KLZ, W1, W2, Ndata,
                                  out + OUT_SCAL);
}

// Round 8
// 590.795 us; speedup vs baseline: 1.0500x; 1.0500x over previous
//
#include <hip/hip_runtime.h>
#include <math.h>

#define N_S 256
#define T_S 20
#define D_S 32
#define NF_S 16
#define Q_S 32
#define HDYN_S 256
#define HDIM_S 1024
#define VSTEPS_S 10
#define DT_S 0.1f
#define LOG2PI_F 1.8378770664093453f

// ---- d_out offsets (floats) ----
#define OUT_XREC 0
#define OUT_QM   5242880
#define OUT_QLV  5259264
#define OUT_ZT   5275648
#define OUT_SCAL 5603328

// ---- workspace offsets (floats) ----
#define WS_A1    0          // conv1-v out [b][16][16][16]
#define WS_A3    0          // conv3-v out (A1 dead)
#define WS_WT1   0          // decoder: 32768  [tap][ci=64][co=32]
#define WS_WT2   32768      //          8192   [tap][ci=32][co=16]
#define WS_WT3   40960      //          256
#define WS_A2    1048576    // conv2-v out
#define WS_S0MU  1572864
#define WS_S0LV  1581056
#define WS_V0MU  1589248
#define WS_V0LV  1597440
#define WS_LOGP  1605632
#define WS_LHOOD 1610752
#define WS_KLZ   1611008
#define WS_TC    1611520
#define TC_S1 (WS_TC + 0)
#define TC_V1 (WS_TC + 256)
#define TC_S2 (WS_TC + 2816)
#define TC_V2 (WS_TC + 11008)
#define TC_S3 (WS_TC + 19200)
#define TC_V3 (WS_TC + 51968)
// ---- s-chain scratch inside d_out XREC region (overwritten by decoder later) ----
#define SC_A1S 0            // 1,048,576
#define SC_A2S 1048576      // 524,288
#define SC_A3S 1572864      // 262,144  (total 1.84M < 5.24M XREC floats)

// ---------------- weight transposes ----------------
__device__ inline void enc_tr(const float* __restrict__ src, float* __restrict__ dst,
                              int e, int CI, int CO) {
    int co = e % CO; int r = e / CO; int tap = r & 15; int ci = r >> 4;
    dst[e] = src[(co * CI + ci) * 16 + tap];
}
__device__ inline void dec_tr(const float* __restrict__ src, float* __restrict__ dst,
                              int e, int CI, int CO) {
    int co = e % CO; int r = e / CO; int ci = r % CI; int tap = r / CI;
    dst[e] = src[(co * CI + ci) * 16 + tap];
}

__global__ __launch_bounds__(256) void prep_enc(
    const float* __restrict__ Cs1, const float* __restrict__ Cv1,
    const float* __restrict__ Cs2, const float* __restrict__ Cv2,
    const float* __restrict__ Cs3, const float* __restrict__ Cv3,
    float* __restrict__ ws)
{
    int idx = blockIdx.x * 256 + threadIdx.x;
    if (blockIdx.x == 0) ws[WS_LHOOD + threadIdx.x] = 0.f;
    if (idx < 256)        enc_tr(Cs1, ws + TC_S1, idx,          1, 16);
    else if (idx < 2816)  enc_tr(Cv1, ws + TC_V1, idx - 256,   10, 16);
    else if (idx < 11008) enc_tr(Cs2, ws + TC_S2, idx - 2816,  16, 32);
    else if (idx < 19200) enc_tr(Cv2, ws + TC_V2, idx - 11008, 16, 32);
    else if (idx < 51968) enc_tr(Cs3, ws + TC_S3, idx - 19200, 32, 64);
    else if (idx < 84736) enc_tr(Cv3, ws + TC_V3, idx - 51968, 32, 64);
}

// ---------------- conv1_both: one 10-ch staging, both encoders' conv1 ----------------
__global__ __launch_bounds__(256) void conv1_both(
    const float* __restrict__ x,
    const float* __restrict__ wtS, const float* __restrict__ wtV,
    const float* __restrict__ bS, const float* __restrict__ bV,
    float* __restrict__ outS, float* __restrict__ outV)
{
    __shared__ float xin[10 * 630];
    __shared__ float wlv[10 * 256];
    __shared__ float wls[256];
    __shared__ float blv[16], bls[16];
    int b = blockIdx.x, yh = blockIdx.y, t = threadIdx.x;
    for (int e = t; e < 10 * 576; e += 256) {
        int ci = e / 576;
        int r = (e >> 5) - ci * 18;
        int cx = e & 31;
        int gy = yh * 16 - 1 + r;
        float v = (gy >= 0 && gy < 32) ? x[(size_t)b * 20480 + ci * 1024 + gy * 32 + cx] : 0.f;
        xin[ci * 630 + r * 35 + cx + 1] = v;
    }
    for (int e = t; e < 10 * 18; e += 256) {
        int ci = e / 18, r = e - ci * 18;
        xin[ci * 630 + r * 35 + 0] = 0.f;
        xin[ci * 630 + r * 35 + 33] = 0.f;
    }
    for (int e = t; e < 10 * 256; e += 256) wlv[e] = wtV[e];
    wls[t] = wtS[t];
    if (t < 16) { blv[t] = bV[t]; bls[t] = bS[t]; }
    __syncthreads();

    int ocq = t >> 7, p = t & 127;
    int oyl = p >> 4, ox = p & 15;
    float accv[8], accs[8];
    #pragma unroll
    for (int j = 0; j < 8; j++) { accv[j] = blv[ocq * 8 + j]; accs[j] = bls[ocq * 8 + j]; }
    for (int ci = 0; ci < 10; ci++) {
        const float* xc = xin + ci * 630;
        const float* wc = wlv + ci * 256 + ocq * 8;
        const float* wcs = wls + ocq * 8;
        bool do_s = (ci == 0);
        #pragma unroll
        for (int ky = 0; ky < 4; ky++) {
            const float* xr = xc + (2 * oyl + ky) * 35;
            #pragma unroll
            for (int kx = 0; kx < 4; kx++) {
                float v = xr[2 * ox + kx];
                const float4* w4 = (const float4*)(wc + (ky * 4 + kx) * 16);
                float4 wa = w4[0], wb = w4[1];
                accv[0] = fmaf(v, wa.x, accv[0]);
                accv[1] = fmaf(v, wa.y, accv[1]);
                accv[2] = fmaf(v, wa.z, accv[2]);
                accv[3] = fmaf(v, wa.w, accv[3]);
                accv[4] = fmaf(v, wb.x, accv[4]);
                accv[5] = fmaf(v, wb.y, accv[5]);
                accv[6] = fmaf(v, wb.z, accv[6]);
                accv[7] = fmaf(v, wb.w, accv[7]);
                if (do_s) {
                    const float4* s4 = (const float4*)(wcs + (ky * 4 + kx) * 16);
                    float4 sa = s4[0], sb = s4[1];
                    accs[0] = fmaf(v, sa.x, accs[0]);
                    accs[1] = fmaf(v, sa.y, accs[1]);
                    accs[2] = fmaf(v, sa.z, accs[2]);
                    accs[3] = fmaf(v, sa.w, accs[3]);
                    accs[4] = fmaf(v, sb.x, accs[4]);
                    accs[5] = fmaf(v, sb.y, accs[5]);
                    accs[6] = fmaf(v, sb.z, accs[6]);
                    accs[7] = fmaf(v, sb.w, accs[7]);
                }
            }
        }
    }
    int oy = yh * 8 + oyl;
    size_t ob = (size_t)b * 4096 + (size_t)(ocq * 8) * 256 + oy * 16 + ox;
    #pragma unroll
    for (int j = 0; j < 8; j++) {
        outV[ob + (size_t)j * 256] = fmaxf(accv[j], 0.f);
        outS[ob + (size_t)j * 256] = fmaxf(accs[j], 0.f);
    }
}

// ---------------- conv2 merged (z = chain) ----------------
__global__ __launch_bounds__(256) void conv2_m(
    const float* __restrict__ a1S, const float* __restrict__ a1V,
    const float* __restrict__ wtS, const float* __restrict__ wtV,
    const float* __restrict__ bS, const float* __restrict__ bV,
    float* __restrict__ outS, float* __restrict__ outV)
{
    __shared__ float xin[16 * 272];
    __shared__ float wl[4096];
    __shared__ float bl[16];
    int b = blockIdx.x, h = blockIdx.y, z = blockIdx.z, t = threadIdx.x;
    const float* a1 = z ? a1V : a1S;
    const float* wt = z ? wtV : wtS;
    const float* bias = z ? bV : bS;
    float* out = z ? outV : outS;
    for (int e = t; e < 4096; e += 256) {
        int ci = e >> 8, r = e & 255, iy = r >> 4, ix = r & 15;
        xin[ci * 272 + iy * 17 + ix] = a1[(size_t)b * 4096 + e];
    }
    for (int e = t; e < 4096; e += 256) {
        int ci = e >> 8, r = e & 255, tap = r >> 4, oc = r & 15;
        wl[e] = wt[ci * 512 + tap * 32 + h * 16 + oc];
    }
    if (t < 16) bl[t] = bias[h * 16 + t];
    __syncthreads();

    int ocq = t >> 6, p = t & 63;
    int pa = p >> 3, pb = p & 7;
    float acc[4];
    #pragma unroll
    for (int j = 0; j < 4; j++) acc[j] = bl[ocq * 4 + j];
    for (int ci = 0; ci < 16; ci++) {
        const float* xc = xin + ci * 272;
        const float* wc = wl + ci * 256 + ocq * 4;
        #pragma unroll
        for (int ky = 0; ky < 4; ky++) {
            int iy = 2 * pa - 1 + ky;
            if ((unsigned)iy >= 16u) continue;
            const float* xr = xc + iy * 17;
            #pragma unroll
            for (int kx = 0; kx < 4; kx++) {
                int ix = 2 * pb - 1 + kx;
                if ((unsigned)ix >= 16u) continue;
                float v = xr[ix];
                float4 wv = *(const float4*)(wc + (ky * 4 + kx) * 16);
                acc[0] = fmaf(v, wv.x, acc[0]);
                acc[1] = fmaf(v, wv.y, acc[1]);
                acc[2] = fmaf(v, wv.z, acc[2]);
                acc[3] = fmaf(v, wv.w, acc[3]);
            }
        }
    }
    size_t ob = (size_t)b * 2048 + (size_t)(h * 16 + ocq * 4) * 64 + pa * 8 + pb;
    #pragma unroll
    for (int j = 0; j < 4; j++) out[ob + (size_t)j * 64] = fmaxf(acc[j], 0.f);
}

// ---------------- conv3 merged (z = chain) ----------------
__global__ __launch_bounds__(256) void conv3_m(
    const float* __restrict__ a2S, const float* __restrict__ a2V,
    const float* __restrict__ wtS, const float* __restrict__ wtV,
    const float* __restrict__ bS, const float* __restrict__ bV,
    float* __restrict__ outS, float* __restrict__ outV)
{
    __shared__ float xin[32 * 72];
    __shared__ float wl[8192];
    __shared__ float bl[16];
    int b = blockIdx.x, h = blockIdx.y, z = blockIdx.z, t = threadIdx.x;
    const float* a2 = z ? a2V : a2S;
    const float* wt = z ? wtV : wtS;
    const float* bias = z ? bV : bS;
    float* out = z ? outV : outS;
    for (int e = t; e < 2048; e += 256) {
        int ci = e >> 6, r = e & 63, iy = r >> 3, ix = r & 7;
        xin[ci * 72 + iy * 9 + ix] = a2[(size_t)b * 2048 + e];
    }
    for (int e = t; e < 8192; e += 256) {
        int ci = e >> 8, r = e & 255, tap = r >> 4, oc = r & 15;
        wl[e] = wt[ci * 1024 + tap * 64 + h * 16 + oc];
    }
    if (t < 16) bl[t] = bias[h * 16 + t];
    __syncthreads();

    int oc = t >> 4, p = t & 15;
    int pa = p >> 2, pb = p & 3;
    float s0 = bl[oc], s1 = 0.f;
    for (int ci = 0; ci < 32; ci += 2) {
        const float* xc0 = xin + ci * 72;
        const float* wc0 = wl + ci * 256 + oc;
        #pragma unroll
        for (int ky = 0; ky < 4; ky++) {
            int iy = 2 * pa - 1 + ky;
            if ((unsigned)iy >= 8u) continue;
            const float* xr0 = xc0 + iy * 9;
            #pragma unroll
            for (int kx = 0; kx < 4; kx++) {
                int ix = 2 * pb - 1 + kx;
                if ((unsigned)ix >= 8u) continue;
                int wi = (ky * 4 + kx) * 16;
                s0 = fmaf(xr0[ix],      wc0[wi],       s0);
                s1 = fmaf(xr0[72 + ix], wc0[256 + wi], s1);
            }
        }
    }
    out[(size_t)b * 1024 + h * 256 + t] = fmaxf(s0 + s1, 0.f);
}

// ---------------- encoder fc merged (y = chain) ----------------
__global__ __launch_bounds__(256) void fc_m(
    const float* __restrict__ hS, const float* __restrict__ hV,
    const float* __restrict__ WsmP, const float* __restrict__ bsmP,
    const float* __restrict__ WslP, const float* __restrict__ bslP,
    const float* __restrict__ WvmP, const float* __restrict__ bvmP,
    const float* __restrict__ WvlP, const float* __restrict__ bvlP,
    float* __restrict__ muS, float* __restrict__ lvS,
    float* __restrict__ muV, float* __restrict__ lvV)
{
    __shared__ float pm[8][32], pl[8][32];
    int b = blockIdx.x, z = blockIdx.y, t = threadIdx.x;
    const float* h  = z ? hV : hS;
    const float* Wm = z ? WvmP : WsmP;
    const float* Wl = z ? WvlP : WslP;
    const float* bm = z ? bvmP : bsmP;
    const float* bl = z ? bvlP : bslP;
    float* mu = z ? muV : muS;
    float* lv = z ? lvV : lvS;
    int q = t & 31, c = t >> 5;
    const float* hb = h + (size_t)b * HDIM_S + c * 128;
    const float* wmp = Wm + (c * 128) * Q_S + q;
    const float* wlp = Wl + (c * 128) * Q_S + q;
    float am = 0.f, al = 0.f;
    #pragma unroll 4
    for (int k = 0; k < 128; k++) {
        float hv = hb[k];
        am = fmaf(hv, wmp[k * Q_S], am);
        al = fmaf(hv, wlp[k * Q_S], al);
    }
    pm[c][q] = am; pl[c][q] = al;
    __syncthreads();
    if (t < 32) {
        float s = bm[t];
        #pragma unroll
        for (int c2 = 0; c2 < 8; c2++) s += pm[c2][t];
        mu[b * Q_S + t] = s;
    } else if (t < 64) {
        int qq = t - 32;
        float s = bl[qq];
        #pragma unroll
        for (int c2 = 0; c2 < 8; c2++) s += pl[c2][qq];
        lv[b * Q_S + qq] = s;
    }
}

// ---------------- reparameterize + decoder weight transpose ----------------
__global__ __launch_bounds__(256) void reparam_prep(
    const float* __restrict__ s0mu, const float* __restrict__ s0lv,
    const float* __restrict__ v0mu, const float* __restrict__ v0lv,
    const float* __restrict__ eps_s, const float* __restrict__ eps_v,
    const float* __restrict__ D1, const float* __restrict__ D2,
    const float* __restrict__ D3,
    float* __restrict__ ws,
    float* __restrict__ qm, float* __restrict__ qlv,
    float* __restrict__ ztL, float* __restrict__ logp)
{
    int n = blockIdx.x, t = threadIdx.x;
    int idx = n * 256 + t;
    if (idx < 32768)      dec_tr(D1, ws + WS_WT1, idx,         64, 32);
    else if (idx < 40960) dec_tr(D2, ws + WS_WT2, idx - 32768, 32, 16);
    else if (idx < 41216) dec_tr(D3, ws + WS_WT3, idx - 40960, 16, 1);
    if (t < 64) {
        int q = t & 31;
        float mu, lvv, ep;
        if (t < 32) { mu = v0mu[n*32+q]; lvv = v0lv[n*32+q]; ep = eps_v[n*32+q]; }
        else        { mu = s0mu[n*32+q]; lvv = s0lv[n*32+q]; ep = eps_s[n*32+q]; }
        float zv = fmaf(ep, expf(lvv), mu);
        qm[n*64 + t]  = mu;
        qlv[n*64 + t] = lvv;
        ztL[(size_t)n * T_S * 64 + t] = zv;
        float e2 = ep * ep;
        #pragma unroll
        for (int off = 32; off; off >>= 1) e2 += __shfl_down(e2, off, 64);
        if (t == 0) logp[n * T_S] = -0.5f * e2 - Q_S * LOG2PI_F;
    }
}

// ---------------- RK4 ODE + fused klz ----------------
__global__ __launch_bounds__(256) void ode_kernel(
    const float* __restrict__ W1, const float* __restrict__ b1,
    const float* __restrict__ W2, const float* __restrict__ b2,
    float* __restrict__ ztL, float* __restrict__ logp, float* __restrict__ klz)
{
    __shared__ float W2s[HDYN_S * Q_S];
    __shared__ float zeval[64];
    __shared__ float hsh[HDYN_S];
    __shared__ float dvred[HDYN_S];
    __shared__ float red4[4];
    int n = blockIdx.x;
    int t = threadIdx.x;

    for (int i = t; i < HDYN_S * Q_S; i += 256) W2s[i] = W2[i];
    float w1r[64];
    #pragma unroll
    for (int j = 0; j < 64; j++) w1r[j] = W1[j * HDYN_S + t];
    float b1r = b1[t];
    __syncthreads();
    float ck = 0.f;
    #pragma unroll
    for (int i = 0; i < Q_S; i++) ck = fmaf(w1r[i], W2s[t * Q_S + i], ck);

    size_t zoff = (size_t)n * T_S * 64;
    float zj = 0.f, ksumj = 0.f, zevalj = 0.f, lp = 0.f, lsum = 0.f, klzacc = 0.f;
    if (t < 64) { zj = ztL[zoff + t]; zevalj = zj; zeval[t] = zj; }
    if (t == 0) lp = logp[n * T_S];
    {
        float e2z = zj * zj;
        #pragma unroll
        for (int off = 32; off; off >>= 1) e2z += __shfl_down(e2z, off, 64);
        if (t == 0) klzacc = lp + 0.5f * e2z + Q_S * LOG2PI_F;
    }

    const float wc[4] = {1.f, 2.f, 2.f, 1.f};
    const float ac[3] = {0.5f * DT_S, 0.5f * DT_S, DT_S};

    for (int step = 1; step < T_S; step++) {
        for (int e = 0; e < 4; e++) {
            __syncthreads();
            float p0 = 0.f, p1 = 0.f, p2 = 0.f, p3 = 0.f;
            const float4* ze4 = (const float4*)zeval;
            #pragma unroll
            for (int jj = 0; jj < 4; jj++) {
                float4 za = ze4[jj], zb = ze4[jj + 4], zc = ze4[jj + 8], zd = ze4[jj + 12];
                p0 = fmaf(za.x, w1r[jj*4+0], p0);
                p0 = fmaf(za.y, w1r[jj*4+1], p0);
                p0 = fmaf(za.z, w1r[jj*4+2], p0);
                p0 = fmaf(za.w, w1r[jj*4+3], p0);
                p1 = fmaf(zb.x, w1r[16+jj*4+0], p1);
                p1 = fmaf(zb.y, w1r[16+jj*4+1], p1);
                p1 = fmaf(zb.z, w1r[16+jj*4+2], p1);
                p1 = fmaf(zb.w, w1r[16+jj*4+3], p1);
                p2 = fmaf(zc.x, w1r[32+jj*4+0], p2);
                p2 = fmaf(zc.y, w1r[32+jj*4+1], p2);
                p2 = fmaf(zc.z, w1r[32+jj*4+2], p2);
                p2 = fmaf(zc.w, w1r[32+jj*4+3], p2);
                p3 = fmaf(zd.x, w1r[48+jj*4+0], p3);
                p3 = fmaf(zd.y, w1r[48+jj*4+1], p3);
                p3 = fmaf(zd.z, w1r[48+jj*4+2], p3);
                p3 = fmaf(zd.w, w1r[48+jj*4+3], p3);
            }
            float pre = b1r + ((p0 + p1) + (p2 + p3));
            float hk = tanhf(pre);
            hsh[t] = hk;
            float gk = (1.f - hk * hk) * ck;
            #pragma unroll
            for (int off = 32; off; off >>= 1) gk += __shfl_down(gk, off, 64);
            if ((t & 63) == 0) red4[t >> 6] = gk;
            __syncthreads();
            {
                int i = t & 31, p = t >> 5;
                const float4* h4 = (const float4*)(hsh + p * 32);
                const float* wbase = W2s + (p * 32) * Q_S + i;
                float a0 = 0.f, a1 = 0.f;
                #pragma unroll
                for (int k4 = 0; k4 < 4; k4++) {
                    float4 ha = h4[k4], hb = h4[k4 + 4];
                    const float* wk = wbase + k4 * 4 * Q_S;
                    a0 = fmaf(ha.x, wk[0],        a0);
                    a0 = fmaf(ha.y, wk[Q_S],      a0);
                    a0 = fmaf(ha.z, wk[2*Q_S],    a0);
                    a0 = fmaf(ha.w, wk[3*Q_S],    a0);
                    const float* wk2 = wbase + (16 + k4 * 4) * Q_S;
                    a1 = fmaf(hb.x, wk2[0],       a1);
                    a1 = fmaf(hb.y, wk2[Q_S],     a1);
                    a1 = fmaf(hb.z, wk2[2*Q_S],   a1);
                    a1 = fmaf(hb.w, wk2[3*Q_S],   a1);
                }
                dvred[t] = a0 + a1;
            }
            __syncthreads();
            if (t < 64) {
                float tr = red4[0] + red4[1] + red4[2] + red4[3];
                float zv_shfl = __shfl(zevalj, (t >= 32) ? (t - 32) : t, 64);
                float kzv;
                if (t < 32) {
                    float dvi = b2[t];
                    #pragma unroll
                    for (int p = 0; p < 8; p++) dvi += dvred[p * 32 + t];
                    kzv = dvi;
                } else kzv = zv_shfl;
                if (e == 0) ksumj = kzv; else ksumj = fmaf(wc[e], kzv, ksumj);
                if (t == 0) { float kl = -tr; lsum = (e == 0) ? kl : fmaf(wc[e], kl, lsum); }
                if (e < 3) {
                    zevalj = fmaf(ac[e], kzv, zj);
                    zeval[t] = zevalj;
                } else {
                    zj = fmaf(DT_S / 6.f, ksumj, zj);
                    zevalj = zj; zeval[t] = zj;
                    ztL[zoff + step * 64 + t] = zj;
                    float e2z = zj * zj;
                    #pragma unroll
                    for (int off = 32; off; off >>= 1) e2z += __shfl_down(e2z, off, 64);
                    if (t == 0) {
                        lp = fmaf(DT_S / 6.f, lsum, lp);
                        logp[n * T_S + step] = lp;
                        klzacc += lp + 0.5f * e2z + Q_S * LOG2PI_F;
                    }
                }
            }
        }
    }
    if (t == 0) klz[n] = klzacc;
}

// ---------------- fused decoder v8 ----------------
// slp: row(iy) 292 fl [73u odd], pos(ix) 72 fl [18u ≡2 mod4] -> dc1 reads bijective
// h1 : plane 592 [148u≡4], row 148 [37u], pos 36 [9u]  (dc2 x-term bijective)
// h2 : plane 1316 [329u], row 164 [41u], pos 20 [5u]
__global__ __launch_bounds__(256) void decoder8(
    const float* __restrict__ ztL, const float* __restrict__ Wf, const float* __restrict__ bf,
    const float* __restrict__ wt1, const float* __restrict__ d1,
    const float* __restrict__ wt2, const float* __restrict__ d2,
    const float* __restrict__ wt3, const float* __restrict__ d3,
    const float* __restrict__ X, float* __restrict__ Xrec, float* __restrict__ lhood)
{
    __shared__ float zs[32];
    __shared__ float h1s[2404];
    __shared__ float u2[5332];
    __shared__ float sh4[4];
    float* slp = u2;
    float* h2p = u2;
    float* xst = h1s;
    const int bidx = blockIdx.x;
    const int t = threadIdx.x;
    const int wu = __builtin_amdgcn_readfirstlane(t >> 6);
    const int l = t & 63;
    const int py = wu >> 1, px = wu & 1;

    if (t < 32) zs[t] = ztL[(size_t)bidx * 64 + 32 + t];
    if (t < 68) u2[5264 + t] = 0.f;
    if (t < 36) h1s[2368 + t] = 0.f;
    __syncthreads();

    // ---- fc3 ----
    {
        float4 acc = ((const float4*)bf)[t];
        const float4* Wf4 = (const float4*)Wf;
        #pragma unroll 4
        for (int q = 0; q < 32; q++) {
            float zq = zs[q];
            float4 wv = Wf4[q * 256 + t];
            acc.x = fmaf(zq, wv.x, acc.x);
            acc.y = fmaf(zq, wv.y, acc.y);
            acc.z = fmaf(zq, wv.z, acc.z);
            acc.w = fmaf(zq, wv.w, acc.w);
        }
        int ci = t >> 2;
        int iy = t & 3;
        float vv[4] = {acc.x, acc.y, acc.z, acc.w};
        #pragma unroll
        for (int j = 0; j < 4; j++)
            slp[iy * 292 + j * 72 + ci] = vv[j];
    }
    __syncthreads();

    // ---- deconv1 ----
    {
        int ocq = l >> 3;
        int pp = l & 7;
        int a_ = pp >> 1, b2 = pp & 1;
        float acc0[4], acc1[4];
        #pragma unroll
        for (int j = 0; j < 4; j++) { acc0[j] = d1[ocq * 4 + j]; acc1[j] = acc0[j]; }
        #pragma unroll
        for (int sy = 0; sy < 2; sy++) {
            int ky = py + 2 * sy;
            int iy = a_ + py + sy - 1;
            bool rowok = (unsigned)iy < 4u;
            #pragma unroll
            for (int sx = 0; sx < 2; sx++) {
                int kx = px + 2 * sx;
                int ix0 = 2 * b2 + px + sx - 1;
                int ix1 = ix0 + 1;
                int off0 = (rowok && (unsigned)ix0 < 4u) ? (iy * 292 + ix0 * 72) : 5264;
                int off1 = (rowok && (unsigned)ix1 < 4u) ? (iy * 292 + ix1 * 72) : 5264;
                const float4* ip0 = (const float4*)(u2 + off0);
                const float4* ip1 = (const float4*)(u2 + off1);
                const float* wb = wt1 + (ky * 4 + kx) * 2048 + ocq * 4;
                #pragma unroll 4
                for (int cc = 0; cc < 16; cc++) {
                    float4 va = ip0[cc];
                    float4 vb = ip1[cc];
                    float av[4] = {va.x, va.y, va.z, va.w};
                    float bv[4] = {vb.x, vb.y, vb.z, vb.w};
                    #pragma unroll
                    for (int r = 0; r < 4; r++) {
                        float4 wv = *(const float4*)(wb + (cc * 4 + r) * 32);
                        acc0[0] = fmaf(av[r], wv.x, acc0[0]); acc1[0] = fmaf(bv[r], wv.x, acc1[0]);
                        acc0[1] = fmaf(av[r], wv.y, acc0[1]); acc1[1] = fmaf(bv[r], wv.y, acc1[1]);
                        acc0[2] = fmaf(av[r], wv.z, acc0[2]); acc1[2] = fmaf(bv[r], wv.z, acc1[2]);
                        acc0[3] = fmaf(av[r], wv.w, acc0[3]); acc1[3] = fmaf(bv[r], wv.w, acc1[3]);
                    }
                }
            }
        }
        float* hp = h1s + (py * 2 + px) * 592;
        int ox0 = 2 * b2, ox1 = ox0 + 1;
        float4 r0, r1;
        r0.x = fmaxf(acc0[0],0.f); r0.y = fmaxf(acc0[1],0.f); r0.z = fmaxf(acc0[2],0.f); r0.w = fmaxf(acc0[3],0.f);
        r1.x = fmaxf(acc1[0],0.f); r1.y = fmaxf(acc1[1],0.f); r1.z = fmaxf(acc1[2],0.f); r1.w = fmaxf(acc1[3],0.f);
        *(float4*)(hp + a_ * 148 + ox0 * 36 + ocq * 4) = r0;
        *(float4*)(hp + a_ * 148 + ox1 * 36 + ocq * 4) = r1;
    }
    __syncthreads();

    // ---- deconv2 ----
    {
        int a = l >> 3, b = l & 7;
        float acc[16];
        #pragma unroll
        for (int j = 0; j < 16; j++) acc[j] = d2[j];
        #pragma unroll
        for (int sy = 0; sy < 2; sy++) {
            int ky = py + 2 * sy;
            int iyf = a + py + sy - 1;
            int pyi = iyf & 1, ly = iyf >> 1;
            bool yok = (unsigned)iyf < 8u;
            #pragma unroll
            for (int sx = 0; sx < 2; sx++) {
                int kx = px + 2 * sx;
                int ixf = b + px + sx - 1;
                int pxi = ixf & 1, lx = ixf >> 1;
                int off = (yok && (unsigned)ixf < 8u)
                          ? ((pyi * 2 + pxi) * 592 + ly * 148 + lx * 36) : 2368;
                const float4* ip4 = (const float4*)(h1s + off);
                const float* wb = wt2 + (ky * 4 + kx) * 512;
                #pragma unroll 2
                for (int cc = 0; cc < 8; cc++) {
                    float4 v = ip4[cc];
                    float vv[4] = {v.x, v.y, v.z, v.w};
                    #pragma unroll
                    for (int r = 0; r < 4; r++) {
                        const float4* wq = (const float4*)(wb + (cc * 4 + r) * 16);
                        float4 w0 = wq[0], w1 = wq[1], w2 = wq[2], w3 = wq[3];
                        float vr = vv[r];
                        acc[0]  = fmaf(vr, w0.x, acc[0]);
                        acc[1]  = fmaf(vr, w0.y, acc[1]);
                        acc[2]  = fmaf(vr, w0.z, acc[2]);
                        acc[3]  = fmaf(vr, w0.w, acc[3]);
                        acc[4]  = fmaf(vr, w1.x, acc[4]);
                        acc[5]  = fmaf(vr, w1.y, acc[5]);
                        acc[6]  = fmaf(vr, w1.z, acc[6]);
                        acc[7]  = fmaf(vr, w1.w, acc[7]);
                        acc[8]  = fmaf(vr, w2.x, acc[8]);
                        acc[9]  = fmaf(vr, w2.y, acc[9]);
                        acc[10] = fmaf(vr, w2.z, acc[10]);
                        acc[11] = fmaf(vr, w2.w, acc[11]);
                        acc[12] = fmaf(vr, w3.x, acc[12]);
                        acc[13] = fmaf(vr, w3.y, acc[13]);
                        acc[14] = fmaf(vr, w3.z, acc[14]);
                        acc[15] = fmaf(vr, w3.w, acc[15]);
                    }
                }
            }
        }
        float* hq = h2p + (py * 2 + px) * 1316 + a * 164 + b * 20;
        #pragma unroll
        for (int j = 0; j < 4; j++) {
            float4 r;
            r.x = fmaxf(acc[j*4+0], 0.f);
            r.y = fmaxf(acc[j*4+1], 0.f);
            r.z = fmaxf(acc[j*4+2], 0.f);
            r.w = fmaxf(acc[j*4+3], 0.f);
            *(float4*)(hq + j * 4) = r;
        }
    }
    __syncthreads();

    // ---- deconv3: 2x2 tile ----
    {
        int u = l >> 3, v = l & 7;
        int ib = 2 * u + py - 1;
        int jb = 2 * v + px - 1;
        int offp[3][3];
        #pragma unroll
        for (int r = 0; r < 3; r++) {
            int iy = ib + r;
            int pyi = iy & 1, ly = iy >> 1;
            bool yok = (unsigned)iy < 16u;
            #pragma unroll
            for (int c = 0; c < 3; c++) {
                int ix = jb + c;
                int pxi = ix & 1, lx = ix >> 1;
                offp[r][c] = (yok && (unsigned)ix < 16u)
                             ? ((pyi * 2 + pxi) * 1316 + ly * 164 + lx * 20) : 5264;
            }
        }
        float d30 = d3[0];
        float acc[4] = {d30, d30, d30, d30};
        #pragma unroll
        for (int cc = 0; cc < 4; cc++) {
            float4 pix[3][3];
            #pragma unroll
            for (int r = 0; r < 3; r++)
                #pragma unroll
                for (int c = 0; c < 3; c++)
                    pix[r][c] = ((const float4*)(u2 + offp[r][c]))[cc];
            #pragma unroll
            for (int sy = 0; sy < 2; sy++) {
                int ky = py + 2 * sy;
                #pragma unroll
                for (int sx = 0; sx < 2; sx++) {
                    int kx = px + 2 * sx;
                    float4 wq = ((const float4*)(wt3 + (ky * 4 + kx) * 16))[cc];
                    #pragma unroll
                    for (int dy = 0; dy < 2; dy++) {
                        #pragma unroll
                        for (int dx = 0; dx < 2; dx++) {
                            float4 p4 = pix[dy + sy][dx + sx];
                            float s = acc[dy * 2 + dx];
                            s = fmaf(p4.x, wq.x, s);
                            s = fmaf(p4.y, wq.y, s);
                            s = fmaf(p4.z, wq.z, s);
                            s = fmaf(p4.w, wq.w, s);
                            acc[dy * 2 + dx] = s;
                        }
                    }
                }
            }
        }
        #pragma unroll
        for (int dy = 0; dy < 2; dy++) {
            #pragma unroll
            for (int dx = 0; dx < 2; dx++) {
                int oy = 4 * u + 2 * dy + py;
                int ox = 4 * v + 2 * dx + px;
                xst[oy * 36 + ox] = 1.f / (1.f + expf(-acc[dy * 2 + dx]));
            }
        }
    }
    __syncthreads();

    // ---- coalesced Xrec write + X read + lhood ----
    {
        int row = t >> 3, col = (t & 7) * 4;
        float4 xr4 = *(const float4*)(xst + row * 36 + col);
        *(float4*)(Xrec + (size_t)bidx * 1024 + t * 4) = xr4;
        float4 xi4 = *(const float4*)(X + (size_t)bidx * 1024 + t * 4);
        float ll = 0.f;
        ll += logf(0.001f + xr4.x) * xi4.x + logf(1.001f - xr4.x) * (1.f - xi4.x);
        ll += logf(0.001f + xr4.y) * xi4.y + logf(1.001f - xr4.y) * (1.f - xi4.y);
        ll += logf(0.001f + xr4.z) * xi4.z + logf(1.001f - xr4.z) * (1.f - xi4.z);
        ll += logf(0.001f + xr4.w) * xi4.w + logf(1.001f - xr4.w) * (1.f - xi4.w);
        #pragma unroll
        for (int off = 32; off; off >>= 1) ll += __shfl_down(ll, off, 64);
        if ((t & 63) == 0) sh4[t >> 6] = ll;
    }
    __syncthreads();
    if (t == 0) atomicAdd(&lhood[bidx / T_S], sh4[0] + sh4[1] + sh4[2] + sh4[3]);
}

// ---------------- final scalars ----------------
__global__ __launch_bounds__(256) void final2(
    const float* __restrict__ lhood, const float* __restrict__ klz,
    const float* __restrict__ W1, const float* __restrict__ W2,
    const int* __restrict__ Ndata, float* __restrict__ outs)
{
    __shared__ float shA[4], shB[4], shC[4];
    int t = threadIdx.x;
    float a = lhood[t];
    float b = klz[t];
    float c = 0.f;
    for (int i = t; i < 64 * HDYN_S; i += 256) c = fmaf(W1[i], W1[i], c);
    for (int i = t; i < HDYN_S * Q_S; i += 256) c = fmaf(W2[i], W2[i], c);
    #pragma unroll
    for (int off = 32; off; off >>= 1) {
        a += __shfl_down(a, off, 64);
        b += __shfl_down(b, off, 64);
        c += __shfl_down(c, off, 64);
    }
    if ((t & 63) == 0) { shA[t >> 6] = a; shB[t >> 6] = b; shC[t >> 6] = c; }
    __syncthreads();
    if (t == 0) {
        float Nd = (float)Ndata[0];
        float lh = Nd * ((shA[0] + shA[1] + shA[2] + shA[3]) / 256.f);
        float kz = Nd * ((shB[0] + shB[1] + shB[2] + shB[3]) / 256.f);
        float bkw = 0.5f * (shC[0] + shC[1] + shC[2] + shC[3]);
        outs[0] = lh - kz - bkw;
        outs[1] = lh;
        outs[2] = kz;
        outs[3] = bkw;
    }
}

extern "C" void kernel_launch(void* const* d_in, const int* in_sizes, int n_in,
                              void* d_out, int out_size, void* d_ws, size_t ws_size,
                              hipStream_t stream) {
    const float* X      = (const float*)d_in[0];
    const float* eps_s0 = (const float*)d_in[1];
    const float* eps_v0 = (const float*)d_in[2];
    const float* Cs1 = (const float*)d_in[3],  *cs1 = (const float*)d_in[4];
    const float* Cs2 = (const float*)d_in[5],  *cs2 = (const float*)d_in[6];
    const float* Cs3 = (const float*)d_in[7],  *cs3 = (const float*)d_in[8];
    const float* Wsm = (const float*)d_in[9],  *bsm = (const float*)d_in[10];
    const float* Wsl = (const float*)d_in[11], *bsl = (const float*)d_in[12];
    const float* Cv1 = (const float*)d_in[13], *cv1 = (const float*)d_in[14];
    const float* Cv2 = (const float*)d_in[15], *cv2 = (const float*)d_in[16];
    const float* Cv3 = (const float*)d_in[17], *cv3 = (const float*)d_in[18];
    const float* Wvm = (const float*)d_in[19], *bvm = (const float*)d_in[20];
    const float* Wvl = (const float*)d_in[21], *bvl = (const float*)d_in[22];
    const float* W1  = (const float*)d_in[23], *b1  = (const float*)d_in[24];
    const float* W2  = (const float*)d_in[25], *b2  = (const float*)d_in[26];
    const float* Wf  = (const float*)d_in[27], *bf  = (const float*)d_in[28];
    const float* D1  = (const float*)d_in[29], *d1  = (const float*)d_in[30];
    const float* D2  = (const float*)d_in[31], *d2  = (const float*)d_in[32];
    const float* D3  = (const float*)d_in[33], *d3  = (const float*)d_in[34];
    const int*   Ndata = (const int*)d_in[35];

    float* out = (float*)d_out;
    float* ws  = (float*)d_ws;
    float* scr = out + OUT_XREC;   // s-chain scratch, overwritten by decoder8 later

    prep_enc<<<331, 256, 0, stream>>>(Cs1, Cv1, Cs2, Cv2, Cs3, Cv3, ws);

    // ---- conv1 (both encoders, one X staging) ----
    conv1_both<<<dim3(256, 2), 256, 0, stream>>>(X, ws + TC_S1, ws + TC_V1, cs1, cv1,
                                                 scr + SC_A1S, ws + WS_A1);

    // ---- conv2/conv3/fc merged over chains ----
    conv2_m<<<dim3(256, 2, 2), 256, 0, stream>>>(scr + SC_A1S, ws + WS_A1,
                                                 ws + TC_S2, ws + TC_V2, cs2, cv2,
                                                 scr + SC_A2S, ws + WS_A2);
    conv3_m<<<dim3(256, 4, 2), 256, 0, stream>>>(scr + SC_A2S, ws + WS_A2,
                                                 ws + TC_S3, ws + TC_V3, cs3, cv3,
                                                 scr + SC_A3S, ws + WS_A3);
    fc_m<<<dim3(256, 2), 256, 0, stream>>>(scr + SC_A3S, ws + WS_A3,
                                           Wsm, bsm, Wsl, bsl, Wvm, bvm, Wvl, bvl,
                                           ws + WS_S0MU, ws + WS_S0LV,
                                           ws + WS_V0MU, ws + WS_V0LV);

    // ---- reparameterize + decoder weight transpose ----
    reparam_prep<<<256, 256, 0, stream>>>(ws + WS_S0MU, ws + WS_S0LV, ws + WS_V0MU, ws + WS_V0LV,
                                          eps_s0, eps_v0, D1, D2, D3, ws,
                                          out + OUT_QM, out + OUT_QLV,
                                          out + OUT_ZT, ws + WS_LOGP);

    // ---- RK4 ODE (+klz) ----
    ode_kernel<<<256, 256, 0, stream>>>(W1, b1, W2, b2, out + OUT_ZT, ws + WS_LOGP,
                                        ws + WS_KLZ);

    // ---- fused decoder ----
    decoder8<<<5120, 256, 0, stream>>>(out + OUT_ZT, Wf, bf,
                                       ws + WS_WT1, d1, ws + WS_WT2, d2, ws + WS_WT3, d3,
                                       X, out + OUT_XREC, ws + WS_LHOOD);

    // ---- final scalars ----
    final2<<<1, 256, 0, stream>>>(ws + WS_LHOOD, ws + WS_KLZ, W1, W2, Ndata,
                                  out + OUT_SCAL);
}

// Round 9
// 586.260 us; speedup vs baseline: 1.0581x; 1.0077x over previous
//
#include <hip/hip_runtime.h>
#include <math.h>

#define N_S 256
#define T_S 20
#define D_S 32
#define NF_S 16
#define Q_S 32
#define HDYN_S 256
#define HDIM_S 1024
#define VSTEPS_S 10
#define DT_S 0.1f
#define LOG2PI_F 1.8378770664093453f

// ---- d_out offsets (floats) ----
#define OUT_XREC 0
#define OUT_QM   5242880
#define OUT_QLV  5259264
#define OUT_ZT   5275648
#define OUT_SCAL 5603328

// ---- workspace offsets (floats) ----
#define WS_A1    0          // conv1-v out
#define WS_A3    0          // conv3-v out (A1 dead)
#define WS_A2    1048576    // conv2-v out
#define WS_S0MU  1572864
#define WS_S0LV  1581056
#define WS_V0MU  1589248
#define WS_V0LV  1597440
#define WS_LHOOD 1610752
#define WS_KLZ   1611008
#define WS_TC    1611520
#define TC_S1 (WS_TC + 0)
#define TC_V1 (WS_TC + 256)
#define TC_S2 (WS_TC + 2816)
#define TC_V2 (WS_TC + 11008)
#define TC_S3 (WS_TC + 19200)
#define TC_V3 (WS_TC + 51968)      // ends 1696256
#define WS_WT1   1703936    // 32768  [tap][ci=64][co=32]
#define WS_WT2   1736704    // 8192   [tap][ci=32][co=16]
#define WS_WT3   1744896    // 256    (end 1745152 fl = 6.98 MB)
// ---- s-chain scratch inside d_out XREC region ----
#define SC_A1S 0
#define SC_A2S 1048576
#define SC_A3S 1572864

// ---------------- weight transposes ----------------
__device__ inline void enc_tr(const float* __restrict__ src, float* __restrict__ dst,
                              int e, int CI, int CO) {
    int co = e % CO; int r = e / CO; int tap = r & 15; int ci = r >> 4;
    dst[e] = src[(co * CI + ci) * 16 + tap];
}
__device__ inline void dec_tr(const float* __restrict__ src, float* __restrict__ dst,
                              int e, int CI, int CO) {
    int co = e % CO; int r = e / CO; int ci = r % CI; int tap = r / CI;
    dst[e] = src[(co * CI + ci) * 16 + tap];
}

// enc transposes + dec transposes + lhood zero, one launch
__global__ __launch_bounds__(256) void prep_all(
    const float* __restrict__ Cs1, const float* __restrict__ Cv1,
    const float* __restrict__ Cs2, const float* __restrict__ Cv2,
    const float* __restrict__ Cs3, const float* __restrict__ Cv3,
    const float* __restrict__ D1, const float* __restrict__ D2,
    const float* __restrict__ D3,
    float* __restrict__ ws)
{
    int idx = blockIdx.x * 256 + threadIdx.x;
    if (blockIdx.x == 0) ws[WS_LHOOD + threadIdx.x] = 0.f;
    if (idx < 256)        enc_tr(Cs1, ws + TC_S1, idx,          1, 16);
    else if (idx < 2816)  enc_tr(Cv1, ws + TC_V1, idx - 256,   10, 16);
    else if (idx < 11008) enc_tr(Cs2, ws + TC_S2, idx - 2816,  16, 32);
    else if (idx < 19200) enc_tr(Cv2, ws + TC_V2, idx - 11008, 16, 32);
    else if (idx < 51968) enc_tr(Cs3, ws + TC_S3, idx - 19200, 32, 64);
    else if (idx < 84736) enc_tr(Cv3, ws + TC_V3, idx - 51968, 32, 64);
    else if (idx < 117504) dec_tr(D1, ws + WS_WT1, idx - 84736,  64, 32);
    else if (idx < 125696) dec_tr(D2, ws + WS_WT2, idx - 117504, 32, 16);
    else if (idx < 125952) dec_tr(D3, ws + WS_WT3, idx - 125696, 16, 1);
}

// ---------------- conv1_both ----------------
__global__ __launch_bounds__(256) void conv1_both(
    const float* __restrict__ x,
    const float* __restrict__ wtS, const float* __restrict__ wtV,
    const float* __restrict__ bS, const float* __restrict__ bV,
    float* __restrict__ outS, float* __restrict__ outV)
{
    __shared__ float xin[10 * 630];
    __shared__ float wlv[10 * 256];
    __shared__ float wls[256];
    __shared__ float blv[16], bls[16];
    int b = blockIdx.x, yh = blockIdx.y, t = threadIdx.x;
    for (int e = t; e < 10 * 576; e += 256) {
        int ci = e / 576;
        int r = (e >> 5) - ci * 18;
        int cx = e & 31;
        int gy = yh * 16 - 1 + r;
        float v = (gy >= 0 && gy < 32) ? x[(size_t)b * 20480 + ci * 1024 + gy * 32 + cx] : 0.f;
        xin[ci * 630 + r * 35 + cx + 1] = v;
    }
    for (int e = t; e < 10 * 18; e += 256) {
        int ci = e / 18, r = e - ci * 18;
        xin[ci * 630 + r * 35 + 0] = 0.f;
        xin[ci * 630 + r * 35 + 33] = 0.f;
    }
    for (int e = t; e < 10 * 256; e += 256) wlv[e] = wtV[e];
    wls[t] = wtS[t];
    if (t < 16) { blv[t] = bV[t]; bls[t] = bS[t]; }
    __syncthreads();

    int ocq = t >> 7, p = t & 127;
    int oyl = p >> 4, ox = p & 15;
    float accv[8], accs[8];
    #pragma unroll
    for (int j = 0; j < 8; j++) { accv[j] = blv[ocq * 8 + j]; accs[j] = bls[ocq * 8 + j]; }
    for (int ci = 0; ci < 10; ci++) {
        const float* xc = xin + ci * 630;
        const float* wc = wlv + ci * 256 + ocq * 8;
        const float* wcs = wls + ocq * 8;
        bool do_s = (ci == 0);
        #pragma unroll
        for (int ky = 0; ky < 4; ky++) {
            const float* xr = xc + (2 * oyl + ky) * 35;
            #pragma unroll
            for (int kx = 0; kx < 4; kx++) {
                float v = xr[2 * ox + kx];
                const float4* w4 = (const float4*)(wc + (ky * 4 + kx) * 16);
                float4 wa = w4[0], wb = w4[1];
                accv[0] = fmaf(v, wa.x, accv[0]);
                accv[1] = fmaf(v, wa.y, accv[1]);
                accv[2] = fmaf(v, wa.z, accv[2]);
                accv[3] = fmaf(v, wa.w, accv[3]);
                accv[4] = fmaf(v, wb.x, accv[4]);
                accv[5] = fmaf(v, wb.y, accv[5]);
                accv[6] = fmaf(v, wb.z, accv[6]);
                accv[7] = fmaf(v, wb.w, accv[7]);
                if (do_s) {
                    const float4* s4 = (const float4*)(wcs + (ky * 4 + kx) * 16);
                    float4 sa = s4[0], sb = s4[1];
                    accs[0] = fmaf(v, sa.x, accs[0]);
                    accs[1] = fmaf(v, sa.y, accs[1]);
                    accs[2] = fmaf(v, sa.z, accs[2]);
                    accs[3] = fmaf(v, sa.w, accs[3]);
                    accs[4] = fmaf(v, sb.x, accs[4]);
                    accs[5] = fmaf(v, sb.y, accs[5]);
                    accs[6] = fmaf(v, sb.z, accs[6]);
                    accs[7] = fmaf(v, sb.w, accs[7]);
                }
            }
        }
    }
    int oy = yh * 8 + oyl;
    size_t ob = (size_t)b * 4096 + (size_t)(ocq * 8) * 256 + oy * 16 + ox;
    #pragma unroll
    for (int j = 0; j < 8; j++) {
        outV[ob + (size_t)j * 256] = fmaxf(accv[j], 0.f);
        outS[ob + (size_t)j * 256] = fmaxf(accs[j], 0.f);
    }
}

// ---------------- conv2 merged ----------------
__global__ __launch_bounds__(256) void conv2_m(
    const float* __restrict__ a1S, const float* __restrict__ a1V,
    const float* __restrict__ wtS, const float* __restrict__ wtV,
    const float* __restrict__ bS, const float* __restrict__ bV,
    float* __restrict__ outS, float* __restrict__ outV)
{
    __shared__ float xin[16 * 272];
    __shared__ float wl[4096];
    __shared__ float bl[16];
    int b = blockIdx.x, h = blockIdx.y, z = blockIdx.z, t = threadIdx.x;
    const float* a1 = z ? a1V : a1S;
    const float* wt = z ? wtV : wtS;
    const float* bias = z ? bV : bS;
    float* out = z ? outV : outS;
    for (int e = t; e < 4096; e += 256) {
        int ci = e >> 8, r = e & 255, iy = r >> 4, ix = r & 15;
        xin[ci * 272 + iy * 17 + ix] = a1[(size_t)b * 4096 + e];
    }
    for (int e = t; e < 4096; e += 256) {
        int ci = e >> 8, r = e & 255, tap = r >> 4, oc = r & 15;
        wl[e] = wt[ci * 512 + tap * 32 + h * 16 + oc];
    }
    if (t < 16) bl[t] = bias[h * 16 + t];
    __syncthreads();

    int ocq = t >> 6, p = t & 63;
    int pa = p >> 3, pb = p & 7;
    float acc[4];
    #pragma unroll
    for (int j = 0; j < 4; j++) acc[j] = bl[ocq * 4 + j];
    for (int ci = 0; ci < 16; ci++) {
        const float* xc = xin + ci * 272;
        const float* wc = wl + ci * 256 + ocq * 4;
        #pragma unroll
        for (int ky = 0; ky < 4; ky++) {
            int iy = 2 * pa - 1 + ky;
            if ((unsigned)iy >= 16u) continue;
            const float* xr = xc + iy * 17;
            #pragma unroll
            for (int kx = 0; kx < 4; kx++) {
                int ix = 2 * pb - 1 + kx;
                if ((unsigned)ix >= 16u) continue;
                float v = xr[ix];
                float4 wv = *(const float4*)(wc + (ky * 4 + kx) * 16);
                acc[0] = fmaf(v, wv.x, acc[0]);
                acc[1] = fmaf(v, wv.y, acc[1]);
                acc[2] = fmaf(v, wv.z, acc[2]);
                acc[3] = fmaf(v, wv.w, acc[3]);
            }
        }
    }
    size_t ob = (size_t)b * 2048 + (size_t)(h * 16 + ocq * 4) * 64 + pa * 8 + pb;
    #pragma unroll
    for (int j = 0; j < 4; j++) out[ob + (size_t)j * 64] = fmaxf(acc[j], 0.f);
}

// ---------------- conv3 merged ----------------
__global__ __launch_bounds__(256) void conv3_m(
    const float* __restrict__ a2S, const float* __restrict__ a2V,
    const float* __restrict__ wtS, const float* __restrict__ wtV,
    const float* __restrict__ bS, const float* __restrict__ bV,
    float* __restrict__ outS, float* __restrict__ outV)
{
    __shared__ float xin[32 * 72];
    __shared__ float wl[8192];
    __shared__ float bl[16];
    int b = blockIdx.x, h = blockIdx.y, z = blockIdx.z, t = threadIdx.x;
    const float* a2 = z ? a2V : a2S;
    const float* wt = z ? wtV : wtS;
    const float* bias = z ? bV : bS;
    float* out = z ? outV : outS;
    for (int e = t; e < 2048; e += 256) {
        int ci = e >> 6, r = e & 63, iy = r >> 3, ix = r & 7;
        xin[ci * 72 + iy * 9 + ix] = a2[(size_t)b * 2048 + e];
    }
    for (int e = t; e < 8192; e += 256) {
        int ci = e >> 8, r = e & 255, tap = r >> 4, oc = r & 15;
        wl[e] = wt[ci * 1024 + tap * 64 + h * 16 + oc];
    }
    if (t < 16) bl[t] = bias[h * 16 + t];
    __syncthreads();

    int oc = t >> 4, p = t & 15;
    int pa = p >> 2, pb = p & 3;
    float s0 = bl[oc], s1 = 0.f;
    for (int ci = 0; ci < 32; ci += 2) {
        const float* xc0 = xin + ci * 72;
        const float* wc0 = wl + ci * 256 + oc;
        #pragma unroll
        for (int ky = 0; ky < 4; ky++) {
            int iy = 2 * pa - 1 + ky;
            if ((unsigned)iy >= 8u) continue;
            const float* xr0 = xc0 + iy * 9;
            #pragma unroll
            for (int kx = 0; kx < 4; kx++) {
                int ix = 2 * pb - 1 + kx;
                if ((unsigned)ix >= 8u) continue;
                int wi = (ky * 4 + kx) * 16;
                s0 = fmaf(xr0[ix],      wc0[wi],       s0);
                s1 = fmaf(xr0[72 + ix], wc0[256 + wi], s1);
            }
        }
    }
    out[(size_t)b * 1024 + h * 256 + t] = fmaxf(s0 + s1, 0.f);
}

// ---------------- encoder fc merged ----------------
__global__ __launch_bounds__(256) void fc_m(
    const float* __restrict__ hS, const float* __restrict__ hV,
    const float* __restrict__ WsmP, const float* __restrict__ bsmP,
    const float* __restrict__ WslP, const float* __restrict__ bslP,
    const float* __restrict__ WvmP, const float* __restrict__ bvmP,
    const float* __restrict__ WvlP, const float* __restrict__ bvlP,
    float* __restrict__ muS, float* __restrict__ lvS,
    float* __restrict__ muV, float* __restrict__ lvV)
{
    __shared__ float pm[8][32], pl[8][32];
    int b = blockIdx.x, z = blockIdx.y, t = threadIdx.x;
    const float* h  = z ? hV : hS;
    const float* Wm = z ? WvmP : WsmP;
    const float* Wl = z ? WvlP : WslP;
    const float* bm = z ? bvmP : bsmP;
    const float* bl = z ? bvlP : bslP;
    float* mu = z ? muV : muS;
    float* lv = z ? lvV : lvS;
    int q = t & 31, c = t >> 5;
    const float* hb = h + (size_t)b * HDIM_S + c * 128;
    const float* wmp = Wm + (c * 128) * Q_S + q;
    const float* wlp = Wl + (c * 128) * Q_S + q;
    float am = 0.f, al = 0.f;
    #pragma unroll 4
    for (int k = 0; k < 128; k++) {
        float hv = hb[k];
        am = fmaf(hv, wmp[k * Q_S], am);
        al = fmaf(hv, wlp[k * Q_S], al);
    }
    pm[c][q] = am; pl[c][q] = al;
    __syncthreads();
    if (t < 32) {
        float s = bm[t];
        #pragma unroll
        for (int c2 = 0; c2 < 8; c2++) s += pm[c2][t];
        mu[b * Q_S + t] = s;
    } else if (t < 64) {
        int qq = t - 32;
        float s = bl[qq];
        #pragma unroll
        for (int c2 = 0; c2 < 8; c2++) s += pl[c2][qq];
        lv[b * Q_S + qq] = s;
    }
}

// ---------------- RK4 ODE + fused reparam + fused klz ----------------
__global__ __launch_bounds__(256) void ode2(
    const float* __restrict__ W1, const float* __restrict__ b1,
    const float* __restrict__ W2, const float* __restrict__ b2,
    const float* __restrict__ s0mu, const float* __restrict__ s0lv,
    const float* __restrict__ v0mu, const float* __restrict__ v0lv,
    const float* __restrict__ eps_s, const float* __restrict__ eps_v,
    float* __restrict__ qm, float* __restrict__ qlv,
    float* __restrict__ ztL, float* __restrict__ klz)
{
    __shared__ float W2s[HDYN_S * Q_S];
    __shared__ float zeval[64];
    __shared__ float hsh[HDYN_S];
    __shared__ float dvred[HDYN_S];
    __shared__ float red4[4];
    int n = blockIdx.x;
    int t = threadIdx.x;

    for (int i = t; i < HDYN_S * Q_S; i += 256) W2s[i] = W2[i];
    float w1r[64];
    #pragma unroll
    for (int j = 0; j < 64; j++) w1r[j] = W1[j * HDYN_S + t];
    float b1r = b1[t];

    // ---- fused reparam (sample n) ----
    size_t zoff = (size_t)n * T_S * 64;
    float zj = 0.f, zevalj = 0.f, lp = 0.f, klzacc = 0.f;
    float ep = 0.f;
    if (t < 64) {
        int q = t & 31;
        float mu, lvv;
        if (t < 32) { mu = v0mu[n*32+q]; lvv = v0lv[n*32+q]; ep = eps_v[n*32+q]; }
        else        { mu = s0mu[n*32+q]; lvv = s0lv[n*32+q]; ep = eps_s[n*32+q]; }
        zj = fmaf(ep, expf(lvv), mu);
        qm[n*64 + t]  = mu;
        qlv[n*64 + t] = lvv;
        ztL[zoff + t] = zj;
        zevalj = zj; zeval[t] = zj;
        float e2 = ep * ep;
        float z2 = zj * zj;
        #pragma unroll
        for (int off = 32; off; off >>= 1) {
            e2 += __shfl_down(e2, off, 64);
            z2 += __shfl_down(z2, off, 64);
        }
        if (t == 0) {
            lp = -0.5f * e2 - Q_S * LOG2PI_F;
            klzacc = lp + 0.5f * z2 + Q_S * LOG2PI_F;
        }
    }
    __syncthreads();
    float ck = 0.f;
    #pragma unroll
    for (int i = 0; i < Q_S; i++) ck = fmaf(w1r[i], W2s[t * Q_S + i], ck);

    float ksumj = 0.f, lsum = 0.f;
    const float wc[4] = {1.f, 2.f, 2.f, 1.f};
    const float ac[3] = {0.5f * DT_S, 0.5f * DT_S, DT_S};

    for (int step = 1; step < T_S; step++) {
        for (int e = 0; e < 4; e++) {
            __syncthreads();
            float p0 = 0.f, p1 = 0.f, p2 = 0.f, p3 = 0.f;
            const float4* ze4 = (const float4*)zeval;
            #pragma unroll
            for (int jj = 0; jj < 4; jj++) {
                float4 za = ze4[jj], zb = ze4[jj + 4], zc = ze4[jj + 8], zd = ze4[jj + 12];
                p0 = fmaf(za.x, w1r[jj*4+0], p0);
                p0 = fmaf(za.y, w1r[jj*4+1], p0);
                p0 = fmaf(za.z, w1r[jj*4+2], p0);
                p0 = fmaf(za.w, w1r[jj*4+3], p0);
                p1 = fmaf(zb.x, w1r[16+jj*4+0], p1);
                p1 = fmaf(zb.y, w1r[16+jj*4+1], p1);
                p1 = fmaf(zb.z, w1r[16+jj*4+2], p1);
                p1 = fmaf(zb.w, w1r[16+jj*4+3], p1);
                p2 = fmaf(zc.x, w1r[32+jj*4+0], p2);
                p2 = fmaf(zc.y, w1r[32+jj*4+1], p2);
                p2 = fmaf(zc.z, w1r[32+jj*4+2], p2);
                p2 = fmaf(zc.w, w1r[32+jj*4+3], p2);
                p3 = fmaf(zd.x, w1r[48+jj*4+0], p3);
                p3 = fmaf(zd.y, w1r[48+jj*4+1], p3);
                p3 = fmaf(zd.z, w1r[48+jj*4+2], p3);
                p3 = fmaf(zd.w, w1r[48+jj*4+3], p3);
            }
            float pre = b1r + ((p0 + p1) + (p2 + p3));
            float hk = tanhf(pre);
            hsh[t] = hk;
            float gk = (1.f - hk * hk) * ck;
            #pragma unroll
            for (int off = 32; off; off >>= 1) gk += __shfl_down(gk, off, 64);
            if ((t & 63) == 0) red4[t >> 6] = gk;
            __syncthreads();
            {
                int i = t & 31, p = t >> 5;
                const float4* h4 = (const float4*)(hsh + p * 32);
                const float* wbase = W2s + (p * 32) * Q_S + i;
                float a0 = 0.f, a1 = 0.f;
                #pragma unroll
                for (int k4 = 0; k4 < 4; k4++) {
                    float4 ha = h4[k4], hb = h4[k4 + 4];
                    const float* wk = wbase + k4 * 4 * Q_S;
                    a0 = fmaf(ha.x, wk[0],        a0);
                    a0 = fmaf(ha.y, wk[Q_S],      a0);
                    a0 = fmaf(ha.z, wk[2*Q_S],    a0);
                    a0 = fmaf(ha.w, wk[3*Q_S],    a0);
                    const float* wk2 = wbase + (16 + k4 * 4) * Q_S;
                    a1 = fmaf(hb.x, wk2[0],       a1);
                    a1 = fmaf(hb.y, wk2[Q_S],     a1);
                    a1 = fmaf(hb.z, wk2[2*Q_S],   a1);
                    a1 = fmaf(hb.w, wk2[3*Q_S],   a1);
                }
                dvred[t] = a0 + a1;
            }
            __syncthreads();
            if (t < 64) {
                float tr = red4[0] + red4[1] + red4[2] + red4[3];
                float zv_shfl = __shfl(zevalj, (t >= 32) ? (t - 32) : t, 64);
                float kzv;
                if (t < 32) {
                    float dvi = b2[t];
                    #pragma unroll
                    for (int p = 0; p < 8; p++) dvi += dvred[p * 32 + t];
                    kzv = dvi;
                } else kzv = zv_shfl;
                if (e == 0) ksumj = kzv; else ksumj = fmaf(wc[e], kzv, ksumj);
                if (t == 0) { float kl = -tr; lsum = (e == 0) ? kl : fmaf(wc[e], kl, lsum); }
                if (e < 3) {
                    zevalj = fmaf(ac[e], kzv, zj);
                    zeval[t] = zevalj;
                } else {
                    zj = fmaf(DT_S / 6.f, ksumj, zj);
                    zevalj = zj; zeval[t] = zj;
                    ztL[zoff + step * 64 + t] = zj;
                    float e2z = zj * zj;
                    #pragma unroll
                    for (int off = 32; off; off >>= 1) e2z += __shfl_down(e2z, off, 64);
                    if (t == 0) {
                        lp = fmaf(DT_S / 6.f, lsum, lp);
                        klzacc += lp + 0.5f * e2z + Q_S * LOG2PI_F;
                    }
                }
            }
        }
    }
    if (t == 0) klz[n] = klzacc;
}

// ---------------- fused decoder v9 (= round-7 measured-best layout) ----------------
// slp: row(iy) 276 fl [69u], pos(ix) 68 fl [17u]; zero-line u2[5264..5331]
// h1 : plane 592 [148u], row 148 [37u], pos 36 [9u]; zero-line h1s[2368..2403]
// h2 : plane 1316 [329u], row 164 [41u], pos 20 [5u]
__global__ __launch_bounds__(256) void decoder9(
    const float* __restrict__ ztL, const float* __restrict__ Wf, const float* __restrict__ bf,
    const float* __restrict__ wt1, const float* __restrict__ d1,
    const float* __restrict__ wt2, const float* __restrict__ d2,
    const float* __restrict__ wt3, const float* __restrict__ d3,
    const float* __restrict__ X, float* __restrict__ Xrec, float* __restrict__ lhood)
{
    __shared__ float zs[32];
    __shared__ float h1s[2404];
    __shared__ float u2[5332];
    __shared__ float sh4[4];
    float* slp = u2;
    float* h2p = u2;
    float* xst = h1s;
    const int bidx = blockIdx.x;
    const int t = threadIdx.x;
    const int wu = __builtin_amdgcn_readfirstlane(t >> 6);
    const int l = t & 63;
    const int py = wu >> 1, px = wu & 1;

    if (t < 32) zs[t] = ztL[(size_t)bidx * 64 + 32 + t];
    if (t < 68) u2[5264 + t] = 0.f;
    if (t < 36) h1s[2368 + t] = 0.f;
    __syncthreads();

    // ---- fc3 ----
    {
        float4 acc = ((const float4*)bf)[t];
        const float4* Wf4 = (const float4*)Wf;
        #pragma unroll 4
        for (int q = 0; q < 32; q++) {
            float zq = zs[q];
            float4 wv = Wf4[q * 256 + t];
            acc.x = fmaf(zq, wv.x, acc.x);
            acc.y = fmaf(zq, wv.y, acc.y);
            acc.z = fmaf(zq, wv.z, acc.z);
            acc.w = fmaf(zq, wv.w, acc.w);
        }
        int ci = t >> 2;
        int iy = t & 3;
        float vv[4] = {acc.x, acc.y, acc.z, acc.w};
        #pragma unroll
        for (int j = 0; j < 4; j++)
            slp[iy * 276 + j * 68 + ci] = vv[j];
    }
    __syncthreads();

    // ---- deconv1 ----
    {
        int ocq = l >> 3;
        int pp = l & 7;
        int a_ = pp >> 1, b2 = pp & 1;
        float acc0[4], acc1[4];
        #pragma unroll
        for (int j = 0; j < 4; j++) { acc0[j] = d1[ocq * 4 + j]; acc1[j] = acc0[j]; }
        #pragma unroll
        for (int sy = 0; sy < 2; sy++) {
            int ky = py + 2 * sy;
            int iy = a_ + py + sy - 1;
            bool rowok = (unsigned)iy < 4u;
            #pragma unroll
            for (int sx = 0; sx < 2; sx++) {
                int kx = px + 2 * sx;
                int ix0 = 2 * b2 + px + sx - 1;
                int ix1 = ix0 + 1;
                int off0 = (rowok && (unsigned)ix0 < 4u) ? (iy * 276 + ix0 * 68) : 5264;
                int off1 = (rowok && (unsigned)ix1 < 4u) ? (iy * 276 + ix1 * 68) : 5264;
                const float4* ip0 = (const float4*)(u2 + off0);
                const float4* ip1 = (const float4*)(u2 + off1);
                const float* wb = wt1 + (ky * 4 + kx) * 2048 + ocq * 4;
                #pragma unroll 4
                for (int cc = 0; cc < 16; cc++) {
                    float4 va = ip0[cc];
                    float4 vb = ip1[cc];
                    float av[4] = {va.x, va.y, va.z, va.w};
                    float bv[4] = {vb.x, vb.y, vb.z, vb.w};
                    #pragma unroll
                    for (int r = 0; r < 4; r++) {
                        float4 wv = *(const float4*)(wb + (cc * 4 + r) * 32);
                        acc0[0] = fmaf(av[r], wv.x, acc0[0]); acc1[0] = fmaf(bv[r], wv.x, acc1[0]);
                        acc0[1] = fmaf(av[r], wv.y, acc0[1]); acc1[1] = fmaf(bv[r], wv.y, acc1[1]);
                        acc0[2] = fmaf(av[r], wv.z, acc0[2]); acc1[2] = fmaf(bv[r], wv.z, acc1[2]);
                        acc0[3] = fmaf(av[r], wv.w, acc0[3]); acc1[3] = fmaf(bv[r], wv.w, acc1[3]);
                    }
                }
            }
        }
        float* hp = h1s + (py * 2 + px) * 592;
        int ox0 = 2 * b2, ox1 = ox0 + 1;
        float4 r0, r1;
        r0.x = fmaxf(acc0[0],0.f); r0.y = fmaxf(acc0[1],0.f); r0.z = fmaxf(acc0[2],0.f); r0.w = fmaxf(acc0[3],0.f);
        r1.x = fmaxf(acc1[0],0.f); r1.y = fmaxf(acc1[1],0.f); r1.z = fmaxf(acc1[2],0.f); r1.w = fmaxf(acc1[3],0.f);
        *(float4*)(hp + a_ * 148 + ox0 * 36 + ocq * 4) = r0;
        *(float4*)(hp + a_ * 148 + ox1 * 36 + ocq * 4) = r1;
    }
    __syncthreads();

    // ---- deconv2 ----
    {
        int a = l >> 3, b = l & 7;
        float acc[16];
        #pragma unroll
        for (int j = 0; j < 16; j++) acc[j] = d2[j];
        #pragma unroll
        for (int sy = 0; sy < 2; sy++) {
            int ky = py + 2 * sy;
            int iyf = a + py + sy - 1;
            int pyi = iyf & 1, ly = iyf >> 1;
            bool yok = (unsigned)iyf < 8u;
            #pragma unroll
            for (int sx = 0; sx < 2; sx++) {
                int kx = px + 2 * sx;
                int ixf = b + px + sx - 1;
                int pxi = ixf & 1, lx = ixf >> 1;
                int off = (yok && (unsigned)ixf < 8u)
                          ? ((pyi * 2 + pxi) * 592 + ly * 148 + lx * 36) : 2368;
                const float4* ip4 = (const float4*)(h1s + off);
                const float* wb = wt2 + (ky * 4 + kx) * 512;
                #pragma unroll 2
                for (int cc = 0; cc < 8; cc++) {
                    float4 v = ip4[cc];
                    float vv[4] = {v.x, v.y, v.z, v.w};
                    #pragma unroll
                    for (int r = 0; r < 4; r++) {
                        const float4* wq = (const float4*)(wb + (cc * 4 + r) * 16);
                        float4 w0 = wq[0], w1 = wq[1], w2 = wq[2], w3 = wq[3];
                        float vr = vv[r];
                        acc[0]  = fmaf(vr, w0.x, acc[0]);
                        acc[1]  = fmaf(vr, w0.y, acc[1]);
                        acc[2]  = fmaf(vr, w0.z, acc[2]);
                        acc[3]  = fmaf(vr, w0.w, acc[3]);
                        acc[4]  = fmaf(vr, w1.x, acc[4]);
                        acc[5]  = fmaf(vr, w1.y, acc[5]);
                        acc[6]  = fmaf(vr, w1.z, acc[6]);
                        acc[7]  = fmaf(vr, w1.w, acc[7]);
                        acc[8]  = fmaf(vr, w2.x, acc[8]);
                        acc[9]  = fmaf(vr, w2.y, acc[9]);
                        acc[10] = fmaf(vr, w2.z, acc[10]);
                        acc[11] = fmaf(vr, w2.w, acc[11]);
                        acc[12] = fmaf(vr, w3.x, acc[12]);
                        acc[13] = fmaf(vr, w3.y, acc[13]);
                        acc[14] = fmaf(vr, w3.z, acc[14]);
                        acc[15] = fmaf(vr, w3.w, acc[15]);
                    }
                }
            }
        }
        float* hq = h2p + (py * 2 + px) * 1316 + a * 164 + b * 20;
        #pragma unroll
        for (int j = 0; j < 4; j++) {
            float4 r;
            r.x = fmaxf(acc[j*4+0], 0.f);
            r.y = fmaxf(acc[j*4+1], 0.f);
            r.z = fmaxf(acc[j*4+2], 0.f);
            r.w = fmaxf(acc[j*4+3], 0.f);
            *(float4*)(hq + j * 4) = r;
        }
    }
    __syncthreads();

    // ---- deconv3: 2x2 tile ----
    {
        int u = l >> 3, v = l & 7;
        int ib = 2 * u + py - 1;
        int jb = 2 * v + px - 1;
        int offp[3][3];
        #pragma unroll
        for (int r = 0; r < 3; r++) {
            int iy = ib + r;
            int pyi = iy & 1, ly = iy >> 1;
            bool yok = (unsigned)iy < 16u;
            #pragma unroll
            for (int c = 0; c < 3; c++) {
                int ix = jb + c;
                int pxi = ix & 1, lx = ix >> 1;
                offp[r][c] = (yok && (unsigned)ix < 16u)
                             ? ((pyi * 2 + pxi) * 1316 + ly * 164 + lx * 20) : 5264;
            }
        }
        float d30 = d3[0];
        float acc[4] = {d30, d30, d30, d30};
        #pragma unroll
        for (int cc = 0; cc < 4; cc++) {
            float4 pix[3][3];
            #pragma unroll
            for (int r = 0; r < 3; r++)
                #pragma unroll
                for (int c = 0; c < 3; c++)
                    pix[r][c] = ((const float4*)(u2 + offp[r][c]))[cc];
            #pragma unroll
            for (int sy = 0; sy < 2; sy++) {
                int ky = py + 2 * sy;
                #pragma unroll
                for (int sx = 0; sx < 2; sx++) {
                    int kx = px + 2 * sx;
                    float4 wq = ((const float4*)(wt3 + (ky * 4 + kx) * 16))[cc];
                    #pragma unroll
                    for (int dy = 0; dy < 2; dy++) {
                        #pragma unroll
                        for (int dx = 0; dx < 2; dx++) {
                            float4 p4 = pix[dy + sy][dx + sx];
                            float s = acc[dy * 2 + dx];
                            s = fmaf(p4.x, wq.x, s);
                            s = fmaf(p4.y, wq.y, s);
                            s = fmaf(p4.z, wq.z, s);
                            s = fmaf(p4.w, wq.w, s);
                            acc[dy * 2 + dx] = s;
                        }
                    }
                }
            }
        }
        #pragma unroll
        for (int dy = 0; dy < 2; dy++) {
            #pragma unroll
            for (int dx = 0; dx < 2; dx++) {
                int oy = 4 * u + 2 * dy + py;
                int ox = 4 * v + 2 * dx + px;
                xst[oy * 36 + ox] = 1.f / (1.f + expf(-acc[dy * 2 + dx]));
            }
        }
    }
    __syncthreads();

    // ---- coalesced Xrec write + X read + lhood ----
    {
        int row = t >> 3, col = (t & 7) * 4;
        float4 xr4 = *(const float4*)(xst + row * 36 + col);
        *(float4*)(Xrec + (size_t)bidx * 1024 + t * 4) = xr4;
        float4 xi4 = *(const float4*)(X + (size_t)bidx * 1024 + t * 4);
        float ll = 0.f;
        ll += logf(0.001f + xr4.x) * xi4.x + logf(1.001f - xr4.x) * (1.f - xi4.x);
        ll += logf(0.001f + xr4.y) * xi4.y + logf(1.001f - xr4.y) * (1.f - xi4.y);
        ll += logf(0.001f + xr4.z) * xi4.z + logf(1.001f - xr4.z) * (1.f - xi4.z);
        ll += logf(0.001f + xr4.w) * xi4.w + logf(1.001f - xr4.w) * (1.f - xi4.w);
        #pragma unroll
        for (int off = 32; off; off >>= 1) ll += __shfl_down(ll, off, 64);
        if ((t & 63) == 0) sh4[t >> 6] = ll;
    }
    __syncthreads();
    if (t == 0) atomicAdd(&lhood[bidx / T_S], sh4[0] + sh4[1] + sh4[2] + sh4[3]);
}

// ---------------- final scalars ----------------
__global__ __launch_bounds__(256) void final2(
    const float* __restrict__ lhood, const float* __restrict__ klz,
    const float* __restrict__ W1, const float* __restrict__ W2,
    const int* __restrict__ Ndata, float* __restrict__ outs)
{
    __shared__ float shA[4], shB[4], shC[4];
    int t = threadIdx.x;
    float a = lhood[t];
    float b = klz[t];
    float c = 0.f;
    for (int i = t; i < 64 * HDYN_S; i += 256) c = fmaf(W1[i], W1[i], c);
    for (int i = t; i < HDYN_S * Q_S; i += 256) c = fmaf(W2[i], W2[i], c);
    #pragma unroll
    for (int off = 32; off; off >>= 1) {
        a += __shfl_down(a, off, 64);
        b += __shfl_down(b, off, 64);
        c += __shfl_down(c, off, 64);
    }
    if ((t & 63) == 0) { shA[t >> 6] = a; shB[t >> 6] = b; shC[t >> 6] = c; }
    __syncthreads();
    if (t == 0) {
        float Nd = (float)Ndata[0];
        float lh = Nd * ((shA[0] + shA[1] + shA[2] + shA[3]) / 256.f);
        float kz = Nd * ((shB[0] + shB[1] + shB[2] + shB[3]) / 256.f);
        float bkw = 0.5f * (shC[0] + shC[1] + shC[2] + shC[3]);
        outs[0] = lh - kz - bkw;
        outs[1] = lh;
        outs[2] = kz;
        outs[3] = bkw;
    }
}

extern "C" void kernel_launch(void* const* d_in, const int* in_sizes, int n_in,
                              void* d_out, int out_size, void* d_ws, size_t ws_size,
                              hipStream_t stream) {
    const float* X      = (const float*)d_in[0];
    const float* eps_s0 = (const float*)d_in[1];
    const float* eps_v0 = (const float*)d_in[2];
    const float* Cs1 = (const float*)d_in[3],  *cs1 = (const float*)d_in[4];
    const float* Cs2 = (const float*)d_in[5],  *cs2 = (const float*)d_in[6];
    const float* Cs3 = (const float*)d_in[7],  *cs3 = (const float*)d_in[8];
    const float* Wsm = (const float*)d_in[9],  *bsm = (const float*)d_in[10];
    const float* Wsl = (const float*)d_in[11], *bsl = (const float*)d_in[12];
    const float* Cv1 = (const float*)d_in[13], *cv1 = (const float*)d_in[14];
    const float* Cv2 = (const float*)d_in[15], *cv2 = (const float*)d_in[16];
    const float* Cv3 = (const float*)d_in[17], *cv3 = (const float*)d_in[18];
    const float* Wvm = (const float*)d_in[19], *bvm = (const float*)d_in[20];
    const float* Wvl = (const float*)d_in[21], *bvl = (const float*)d_in[22];
    const float* W1  = (const float*)d_in[23], *b1  = (const float*)d_in[24];
    const float* W2  = (const float*)d_in[25], *b2  = (const float*)d_in[26];
    const float* Wf  = (const float*)d_in[27], *bf  = (const float*)d_in[28];
    const float* D1  = (const float*)d_in[29], *d1  = (const float*)d_in[30];
    const float* D2  = (const float*)d_in[31], *d2  = (const float*)d_in[32];
    const float* D3  = (const float*)d_in[33], *d3  = (const float*)d_in[34];
    const int*   Ndata = (const int*)d_in[35];

    float* out = (float*)d_out;
    float* ws  = (float*)d_ws;
    float* scr = out + OUT_XREC;   // s-chain scratch, overwritten by decoder9 later

    prep_all<<<492, 256, 0, stream>>>(Cs1, Cv1, Cs2, Cv2, Cs3, Cv3, D1, D2, D3, ws);

    // ---- conv1 (both encoders, one X staging) ----
    conv1_both<<<dim3(256, 2), 256, 0, stream>>>(X, ws + TC_S1, ws + TC_V1, cs1, cv1,
                                                 scr + SC_A1S, ws + WS_A1);

    // ---- conv2/conv3/fc merged over chains ----
    conv2_m<<<dim3(256, 2, 2), 256, 0, stream>>>(scr + SC_A1S, ws + WS_A1,
                                                 ws + TC_S2, ws + TC_V2, cs2, cv2,
                                                 scr + SC_A2S, ws + WS_A2);
    conv3_m<<<dim3(256, 4, 2), 256, 0, stream>>>(scr + SC_A2S, ws + WS_A2,
                                                 ws + TC_S3, ws + TC_V3, cs3, cv3,
                                                 scr + SC_A3S, ws + WS_A3);
    fc_m<<<dim3(256, 2), 256, 0, stream>>>(scr + SC_A3S, ws + WS_A3,
                                           Wsm, bsm, Wsl, bsl, Wvm, bvm, Wvl, bvl,
                                           ws + WS_S0MU, ws + WS_S0LV,
                                           ws + WS_V0MU, ws + WS_V0LV);

    // ---- RK4 ODE (+reparam, +klz) ----
    ode2<<<256, 256, 0, stream>>>(W1, b1, W2, b2,
                                  ws + WS_S0MU, ws + WS_S0LV, ws + WS_V0MU, ws + WS_V0LV,
                                  eps_s0, eps_v0,
                                  out + OUT_QM, out + OUT_QLV,
                                  out + OUT_ZT, ws + WS_KLZ);

    // ---- fused decoder ----
    decoder9<<<5120, 256, 0, stream>>>(out + OUT_ZT, Wf, bf,
                                       ws + WS_WT1, d1, ws + WS_WT2, d2, ws + WS_WT3, d3,
                                       X, out + OUT_XREC, ws + WS_LHOOD);

    // ---- final scalars ----
    final2<<<1, 256, 0, stream>>>(ws + WS_LHOOD, ws + WS_KLZ, W1, W2, Ndata,
                                  out + OUT_SCAL);
}